// Round 8
// baseline (14167.461 us; speedup 1.0000x reference)
//
#include <hip/hip_runtime.h>
#include <hip/hip_bf16.h>
#include <cstdint>
#include <cstddef>

#define T_SEQ   512
#define BATCH   8
#define BT      4096
#define DMODEL  1024
#define NHEAD   16
#define HSZ     64
#define NLAYER  8
#define DFF     4096
#define VOCAB   32000
#define EPS     1e-6f
#define NEG_SLOPE 0.1f
#define QLD     3072    // fused qkv row stride

typedef __attribute__((ext_vector_type(8))) short short8;
typedef __attribute__((ext_vector_type(4))) float f32x4;
typedef __hip_bfloat16 bf16;

#define AS1 __attribute__((address_space(1)))
#define AS3 __attribute__((address_space(3)))

// counted-vmcnt wait fused with barrier (T4): the N newest vmem ops (the
// just-issued prefetch) stay in flight across the barrier.
#define WAIT_BAR(N) asm volatile("s_waitcnt vmcnt(" #N ")\ns_barrier" ::: "memory")
#define LGKM_BAR()  asm volatile("s_waitcnt lgkmcnt(0)\ns_barrier" ::: "memory")

// ---------------------------------------------------------------------------
__global__ void embed_kernel(const int* __restrict__ idx,
                             const float* __restrict__ tok,
                             const float* __restrict__ pos,
                             float* __restrict__ x) {
    int bt  = blockIdx.x;
    int tid = threadIdx.x;
    int token = idx[bt];
    int t = bt & (T_SEQ - 1);
    float4 a = reinterpret_cast<const float4*>(tok + (size_t)token * DMODEL)[tid];
    float4 p = reinterpret_cast<const float4*>(pos + (size_t)t * DMODEL)[tid];
    reinterpret_cast<float4*>(x + (size_t)bt * DMODEL)[tid] =
        make_float4(a.x + p.x, a.y + p.y, a.z + p.z, a.w + p.w);
}

// ---------------------------------------------------------------------------
__device__ __forceinline__ void split3v(float v, bf16& h, bf16& m, bf16& l) {
    h = __float2bfloat16(v);
    float r1 = v - __bfloat162float(h);
    m = __float2bfloat16(r1);
    float r2 = r1 - __bfloat162float(m);
    l = __float2bfloat16(r2);
}

// ---------------------------------------------------------------------------
__global__ void rms_split(const float* __restrict__ x,
                          const float* __restrict__ w,
                          bf16* __restrict__ out, size_t planeStride) {
    int row = blockIdx.x;
    int tid = threadIdx.x;
    float4 v = reinterpret_cast<const float4*>(x + (size_t)row * DMODEL)[tid];
    float ss = v.x * v.x + v.y * v.y + v.z * v.z + v.w * v.w;
#pragma unroll
    for (int off = 32; off > 0; off >>= 1) ss += __shfl_xor(ss, off);
    __shared__ float wsum[4];
    if ((tid & 63) == 0) wsum[tid >> 6] = ss;
    __syncthreads();
    float tot = wsum[0] + wsum[1] + wsum[2] + wsum[3];
    float scale = rsqrtf(tot * (1.0f / DMODEL) + EPS);
    float4 wv = reinterpret_cast<const float4*>(w)[tid];
    float o[4] = {v.x * scale * wv.x, v.y * scale * wv.y,
                  v.z * scale * wv.z, v.w * scale * wv.w};
    size_t base = (size_t)row * DMODEL + tid * 4;
#pragma unroll
    for (int j = 0; j < 4; ++j) {
        bf16 h, m, l;
        split3v(o[j], h, m, l);
        out[base + j] = h;
        out[planeStride + base + j] = m;
        out[2 * planeStride + base + j] = l;
    }
}

// ---------------------------------------------------------------------------
__global__ __launch_bounds__(256)
void transpose_split(const float* __restrict__ in, bf16* __restrict__ out,
                     size_t planeStride, int nPlanes, int R, int C,
                     long izs, long ozi) {
    int z = blockIdx.z;
    in  += (size_t)z * izs;
    out += (size_t)z * ozi;
    __shared__ float tile[32][33];
    int r0 = blockIdx.y << 5, c0 = blockIdx.x << 5;
    int tx = threadIdx.x & 31, ty = threadIdx.x >> 5;
#pragma unroll
    for (int i = 0; i < 4; ++i) {
        int r = ty + (i << 3);
        tile[r][tx] = in[(size_t)(r0 + r) * C + c0 + tx];
    }
    __syncthreads();
#pragma unroll
    for (int i = 0; i < 4; ++i) {
        int c = ty + (i << 3);
        float v = tile[tx][c];
        size_t o = (size_t)(c0 + c) * R + r0 + tx;
        bf16 h = __float2bfloat16(v);
        out[o] = h;
        if (nPlanes > 1) {
            float r1 = v - __bfloat162float(h);
            bf16 m = __float2bfloat16(r1);
            out[planeStride + o] = m;
            if (nPlanes > 2) {
                float r2 = r1 - __bfloat162float(m);
                out[2 * planeStride + o] = __float2bfloat16(r2);
            }
        }
    }
}

// concat per-layer qkv bias into (L, 3072) f32
__global__ void cat_bias(const float* __restrict__ bq, const float* __restrict__ bk,
                         const float* __restrict__ bv, float* __restrict__ cb) {
    int i = blockIdx.x * 256 + threadIdx.x;
    int l = i / QLD, r = i - l * QLD;
    const float* src = (r < 1024) ? bq : ((r < 2048) ? bk : bv);
    cb[i] = src[l * 1024 + (r & 1023)];
}

// ---------------------------------------------------------------------------
// WIDE merged-pass split GEMM: block 256(m) x 128(n), 512 thr / 8 waves
// (wave grid 4m x 2n, per-wave 64x64, acc 4x4). Double-buffered LDS with
// counted-vmcnt prefetch. Used for QKV (N=3072) and W1 (N=4096), NP=6.
template <int NP, bool LRELU, bool SPLITOUT>
__global__ __launch_bounds__(512, 2)
void gemm_wide(const bf16* __restrict__ A, size_t aPS,
               const bf16* __restrict__ Bt, size_t bPS,
               const float* __restrict__ bias,
               const float* __restrict__ resid,
               float* __restrict__ C, bf16* __restrict__ Cp, size_t cPS,
               int N, int K) {
    constexpr int NPA = (NP == 6) ? 3 : 2;
    constexpr int NPB = (NP == 6) ? 3 : 2;
    constexpr int PA[6] = {1, 0, 2, 0, 1, 0};   // mm,hl,lh,hm,mh,hh
    constexpr int PB[6] = {1, 2, 0, 1, 0, 0};
    __shared__ bf16 As[2][NPA * 8192];    // 256 rows x 32 k per plane
    __shared__ bf16 Bs[2][NPB * 4096];    // 128 rows x 32 k per plane

    int chunk = gridDim.x >> 3;
    int bid = blockIdx.x;
    int sw = (bid & 7) * chunk + (bid >> 3);
    int m0 = (sw & 15) << 8;
    int n0 = (sw >> 4) << 7;

    const int tid  = threadIdx.x;
    const int lane = tid & 63;
    const int wid  = tid >> 6;

    const int ssk = (((lane & 3) ^ ((lane >> 3) & 3)) << 3);
    size_t offA[2];
#pragma unroll
    for (int i = 0; i < 2; ++i)
        offA[i] = (size_t)(m0 + (wid * 2 + i) * 16 + (lane >> 2)) * K + ssk;
    const size_t offB = (size_t)(n0 + wid * 16 + (lane >> 2)) * K + ssk;

    f32x4 acc[4][4];
#pragma unroll
    for (int i = 0; i < 4; ++i)
#pragma unroll
        for (int j = 0; j < 4; ++j) acc[i][j] = (f32x4){0.f, 0.f, 0.f, 0.f};

    const int wr = wid >> 1, wc = wid & 1;
    const int fm = lane & 15;
    const int rslot = (((lane >> 4) ^ ((lane >> 1) & 3)) & 3) << 3;
    int foffA[4], foffB[4];
#pragma unroll
    for (int i = 0; i < 4; ++i) foffA[i] = (wr * 64 + i * 16 + fm) * 32 + rslot;
#pragma unroll
    for (int j = 0; j < 4; ++j) foffB[j] = (wc * 64 + j * 16 + fm) * 32 + rslot;

    auto STAGE = [&](int buf, int k0) {
#pragma unroll
        for (int pp = 0; pp < NPA; ++pp)
#pragma unroll
            for (int i = 0; i < 2; ++i)
                __builtin_amdgcn_global_load_lds(
                    (const AS1 void*)(A + pp * aPS + offA[i] + k0),
                    (AS3 void*)(&As[buf][pp * 8192 + (wid * 2 + i) * 512]), 16, 0, 0);
#pragma unroll
        for (int pp = 0; pp < NPB; ++pp)
            __builtin_amdgcn_global_load_lds(
                (const AS1 void*)(Bt + pp * bPS + offB + k0),
                (AS3 void*)(&Bs[buf][pp * 4096 + wid * 512]), 16, 0, 0);
    };

    const int nt = K >> 5;
    STAGE(0, 0);
    int cur = 0;
    for (int t = 0; t < nt; ++t) {
        if (t + 1 < nt) {
            STAGE(cur ^ 1, (t + 1) << 5);
            if constexpr (NP == 6) WAIT_BAR(9); else WAIT_BAR(6);
        } else {
            WAIT_BAR(0);
        }

        short8 af[NPA][4], bfr[NPB][4];
#pragma unroll
        for (int pp = 0; pp < NPA; ++pp)
#pragma unroll
            for (int i = 0; i < 4; ++i)
                af[pp][i] = *(const short8*)(&As[cur][pp * 8192 + foffA[i]]);
#pragma unroll
        for (int pp = 0; pp < NPB; ++pp)
#pragma unroll
            for (int j = 0; j < 4; ++j)
                bfr[pp][j] = *(const short8*)(&Bs[cur][pp * 4096 + foffB[j]]);

#pragma unroll
        for (int pp = 6 - NP; pp < 6; ++pp)
#pragma unroll
            for (int i = 0; i < 4; ++i)
#pragma unroll
                for (int j = 0; j < 4; ++j)
                    acc[i][j] = __builtin_amdgcn_mfma_f32_16x16x32_bf16(
                        af[PA[pp]][i], bfr[PB[pp]][j], acc[i][j], 0, 0, 0);
        LGKM_BAR();
        cur ^= 1;
    }

#pragma unroll
    for (int i = 0; i < 4; ++i) {
        int mbase = m0 + wr * 64 + i * 16 + ((lane >> 4) << 2);
#pragma unroll
        for (int j = 0; j < 4; ++j) {
            int n = n0 + wc * 64 + j * 16 + fm;
            float bv = bias[n];
#pragma unroll
            for (int rr = 0; rr < 4; ++rr) {
                int m = mbase + rr;
                float v = acc[i][j][rr] + bv;
                if (LRELU) v = (v >= 0.f) ? v : NEG_SLOPE * v;
                size_t o = (size_t)m * N + n;
                if (SPLITOUT) {
                    bf16 h, mm, ll;
                    split3v(v, h, mm, ll);
                    Cp[o] = h;
                    Cp[cPS + o] = mm;
                    Cp[2 * cPS + o] = ll;
                } else {
                    if (resid) v += resid[o];
                    C[o] = v;
                }
            }
        }
    }
}

// ---------------------------------------------------------------------------
// NARROW merged-pass split GEMM (128x128, 8 waves 2m x 4n, 64x32/wave) with
// counted-vmcnt. NP6: O-proj/W2 (96KB LDS). NP3: vocab (64KB LDS, 2 blk/CU).
template <int NP, bool LRELU>
__global__ __launch_bounds__(512, 2)
void gemm_nar(const bf16* __restrict__ A, size_t aPS,
              const bf16* __restrict__ Bt, size_t bPS,
              const float* __restrict__ bias,
              const float* __restrict__ resid,
              float* __restrict__ C, int N, int K) {
    constexpr int NPA = (NP == 6) ? 3 : 2;
    constexpr int NPB = (NP == 6) ? 3 : 2;
    constexpr int PA[6] = {1, 0, 2, 0, 1, 0};
    constexpr int PB[6] = {1, 2, 0, 1, 0, 0};
    __shared__ bf16 As[2][NPA * 4096];
    __shared__ bf16 Bs[2][NPB * 4096];

    int chunk = gridDim.x >> 3;
    int bid = blockIdx.x;
    int sw = (bid & 7) * chunk + (bid >> 3);
    int m0 = (sw & 31) << 7;
    int n0 = (sw >> 5) << 7;

    const int tid  = threadIdx.x;
    const int lane = tid & 63;
    const int wid  = tid >> 6;

    const int ssk = (((tid & 3) ^ ((tid >> 3) & 3)) << 3);
    const size_t offA = (size_t)(m0 + (tid >> 2)) * K + ssk;
    const size_t offB = (size_t)(n0 + (tid >> 2)) * K + ssk;
    const int ldst = wid * 512;

    f32x4 acc[4][2];
#pragma unroll
    for (int i = 0; i < 4; ++i)
#pragma unroll
        for (int j = 0; j < 2; ++j) acc[i][j] = (f32x4){0.f, 0.f, 0.f, 0.f};

    const int wr = wid >> 2, wc = wid & 3;
    const int fm = lane & 15;
    const int rslot = (((lane >> 4) ^ ((lane >> 1) & 3)) & 3) << 3;
    int foffA[4], foffB[2];
#pragma unroll
    for (int i = 0; i < 4; ++i) foffA[i] = (wr * 64 + i * 16 + fm) * 32 + rslot;
#pragma unroll
    for (int j = 0; j < 2; ++j) foffB[j] = (wc * 32 + j * 16 + fm) * 32 + rslot;

    auto STAGE = [&](int buf, int k0) {
#pragma unroll
        for (int pp = 0; pp < NPA; ++pp)
            __builtin_amdgcn_global_load_lds(
                (const AS1 void*)(A + pp * aPS + offA + k0),
                (AS3 void*)(&As[buf][pp * 4096 + ldst]), 16, 0, 0);
#pragma unroll
        for (int pp = 0; pp < NPB; ++pp)
            __builtin_amdgcn_global_load_lds(
                (const AS1 void*)(Bt + pp * bPS + offB + k0),
                (AS3 void*)(&Bs[buf][pp * 4096 + ldst]), 16, 0, 0);
    };

    const int nt = K >> 5;
    STAGE(0, 0);
    int cur = 0;
    for (int t = 0; t < nt; ++t) {
        if (t + 1 < nt) {
            STAGE(cur ^ 1, (t + 1) << 5);
            if constexpr (NP == 6) WAIT_BAR(6); else WAIT_BAR(4);
        } else {
            WAIT_BAR(0);
        }

        short8 af[NPA][4], bfr[NPB][2];
#pragma unroll
        for (int pp = 0; pp < NPA; ++pp)
#pragma unroll
            for (int i = 0; i < 4; ++i)
                af[pp][i] = *(const short8*)(&As[cur][pp * 4096 + foffA[i]]);
#pragma unroll
        for (int pp = 0; pp < NPB; ++pp)
#pragma unroll
            for (int j = 0; j < 2; ++j)
                bfr[pp][j] = *(const short8*)(&Bs[cur][pp * 4096 + foffB[j]]);

#pragma unroll
        for (int pp = 6 - NP; pp < 6; ++pp)
#pragma unroll
            for (int i = 0; i < 4; ++i)
#pragma unroll
                for (int j = 0; j < 2; ++j)
                    acc[i][j] = __builtin_amdgcn_mfma_f32_16x16x32_bf16(
                        af[PA[pp]][i], bfr[PB[pp]][j], acc[i][j], 0, 0, 0);
        LGKM_BAR();
        cur ^= 1;
    }

#pragma unroll
    for (int i = 0; i < 4; ++i) {
        int mbase = m0 + wr * 64 + i * 16 + ((lane >> 4) << 2);
#pragma unroll
        for (int j = 0; j < 2; ++j) {
            int n = n0 + wc * 32 + j * 16 + fm;
            float bv = bias[n];
#pragma unroll
            for (int rr = 0; rr < 4; ++rr) {
                int m = mbase + rr;
                float v = acc[i][j][rr] + bv;
                if (LRELU) v = (v >= 0.f) ? v : NEG_SLOPE * v;
                size_t o = (size_t)m * N + n;
                if (resid) v += resid[o];
                C[o] = v;
            }
        }
    }
}

// ---------------------------------------------------------------------------
// Fused attention, 1-wave blocks, 8x8 per-thread tiles (halves LDS B/FLOP;
// q/k frag reads are broadcast or 2-way within the wave -> conflict-free).
// Block: one 64-row q-tile of one (b,h). 64 threads as 8(ty: t-rows) x 8(tx).
template <int CAUSAL>
__global__ __launch_bounds__(64)
void attn_fused(const float* __restrict__ qkv, bf16* __restrict__ outp,
                size_t planeStride) {
    int bh = blockIdx.y;
    int b = bh >> 4, h = bh & 15;
    int t0 = blockIdx.x << 6;
    __shared__ float Qst[64][68];   // [e][t]
    __shared__ float KPs[64][68];   // K as [e][s], then P as [s][t]
    __shared__ float Vs[64][68];    // [s][e]
    const int tid = threadIdx.x;
    const int tx = tid & 7, ty = tid >> 3;
    const int lr = tid >> 4, le = (tid & 15) << 2;   // loader coords (4 rows/pass)

    // load Q transposed: Qst[e][t]
    const float* qb = qkv + (size_t)(b * T_SEQ + t0) * QLD + h * HSZ;
#pragma unroll
    for (int r = 0; r < 16; ++r) {
        int row = lr + (r << 2);
        float4 qv = *reinterpret_cast<const float4*>(qb + (size_t)row * QLD + le);
        Qst[le + 0][row] = qv.x;
        Qst[le + 1][row] = qv.y;
        Qst[le + 2][row] = qv.z;
        Qst[le + 3][row] = qv.w;
    }

    float o[8][8] = {};
    float mrow[8], lrow[8];
#pragma unroll
    for (int i = 0; i < 8; ++i) { mrow[i] = -INFINITY; lrow[i] = 0.f; }

    const int NT = CAUSAL ? (blockIdx.x + 1) : (T_SEQ / 64);
    for (int st = 0; st < NT; ++st) {
        int s0 = st << 6;
        const float* kb = qkv + 1024 + (size_t)(b * T_SEQ + s0) * QLD + h * HSZ;
        const float* vb = qkv + 2048 + (size_t)(b * T_SEQ + s0) * QLD + h * HSZ;
#pragma unroll
        for (int r = 0; r < 16; ++r) {
            int row = lr + (r << 2);
            float4 kv = *reinterpret_cast<const float4*>(kb + (size_t)row * QLD + le);
            KPs[le + 0][row] = kv.x;
            KPs[le + 1][row] = kv.y;
            KPs[le + 2][row] = kv.z;
            KPs[le + 3][row] = kv.w;
            float4 vv = *reinterpret_cast<const float4*>(vb + (size_t)row * QLD + le);
            *reinterpret_cast<float4*>(&Vs[row][le]) = vv;
        }
        __syncthreads();

        // S = 8 * Q.K^T  (8x8 per thread)
        float s[8][8] = {};
        for (int e = 0; e < 64; ++e) {
            float4 q0 = *reinterpret_cast<const float4*>(&Qst[e][ty << 3]);
            float4 q1 = *reinterpret_cast<const float4*>(&Qst[e][(ty << 3) + 4]);
            float4 k0 = *reinterpret_cast<const float4*>(&KPs[e][tx << 3]);
            float4 k1 = *reinterpret_cast<const float4*>(&KPs[e][(tx << 3) + 4]);
            float av[8] = {q0.x, q0.y, q0.z, q0.w, q1.x, q1.y, q1.z, q1.w};
            float bv[8] = {k0.x, k0.y, k0.z, k0.w, k1.x, k1.y, k1.z, k1.w};
#pragma unroll
            for (int i = 0; i < 8; ++i)
#pragma unroll
                for (int j = 0; j < 8; ++j) s[i][j] += av[i] * bv[j];
        }
#pragma unroll
        for (int i = 0; i < 8; ++i)
#pragma unroll
            for (int j = 0; j < 8; ++j) {
                float v = 8.0f * s[i][j];
                if (CAUSAL) {
                    int scol = s0 + (tx << 3) + j;
                    int trow = t0 + (ty << 3) + i;
                    if (scol > trow) v = -INFINITY;
                }
                s[i][j] = v;
            }

        // online softmax: row stats across the 8-lane tx group
#pragma unroll
        for (int i = 0; i < 8; ++i) {
            float rmax = -INFINITY;
#pragma unroll
            for (int j = 0; j < 8; ++j) rmax = fmaxf(rmax, s[i][j]);
#pragma unroll
            for (int msk = 1; msk < 8; msk <<= 1)
                rmax = fmaxf(rmax, __shfl_xor(rmax, msk));
            float mn = fmaxf(mrow[i], rmax);
            float fsc = __expf(mrow[i] - mn);
            float rs = 0.f;
#pragma unroll
            for (int j = 0; j < 8; ++j) {
                float pv = __expf(s[i][j] - mn);
                s[i][j] = pv;
                rs += pv;
            }
#pragma unroll
            for (int msk = 1; msk < 8; msk <<= 1) rs += __shfl_xor(rs, msk);
            lrow[i] = lrow[i] * fsc + rs;
            mrow[i] = mn;
#pragma unroll
            for (int j = 0; j < 8; ++j) o[i][j] *= fsc;
        }
        __syncthreads();    // all threads done reading K before P overwrites

        // write P transposed into KPs: [s][t]
#pragma unroll
        for (int i = 0; i < 8; ++i)
#pragma unroll
            for (int j = 0; j < 8; ++j)
                KPs[(tx << 3) + j][(ty << 3) + i] = s[i][j];
        __syncthreads();

        // O += P.V
        for (int kk = 0; kk < 64; ++kk) {
            float4 p0 = *reinterpret_cast<const float4*>(&KPs[kk][ty << 3]);
            float4 p1 = *reinterpret_cast<const float4*>(&KPs[kk][(ty << 3) + 4]);
            float4 v0 = *reinterpret_cast<const float4*>(&Vs[kk][tx << 3]);
            float4 v1 = *reinterpret_cast<const float4*>(&Vs[kk][(tx << 3) + 4]);
            float av[8] = {p0.x, p0.y, p0.z, p0.w, p1.x, p1.y, p1.z, p1.w};
            float bv[8] = {v0.x, v0.y, v0.z, v0.w, v1.x, v1.y, v1.z, v1.w};
#pragma unroll
            for (int i = 0; i < 8; ++i)
#pragma unroll
                for (int j = 0; j < 8; ++j) o[i][j] += av[i] * bv[j];
        }
        __syncthreads();
    }

    // epilogue: normalize + split3 store
#pragma unroll
    for (int i = 0; i < 8; ++i) {
        float inv = 1.f / lrow[i];
        size_t orow = (size_t)(b * T_SEQ + t0 + (ty << 3) + i) * DMODEL
                      + h * HSZ + (tx << 3);
#pragma unroll
        for (int j = 0; j < 8; ++j) {
            bf16 h_, m_, l_;
            split3v(o[i][j] * inv, h_, m_, l_);
            outp[orow + j] = h_;
            outp[planeStride + orow + j] = m_;
            outp[2 * planeStride + orow + j] = l_;
        }
    }
}

// ---------------------------------------------------------------------------
extern "C" void kernel_launch(void* const* d_in, const int* in_sizes, int n_in,
                              void* d_out, int out_size, void* d_ws, size_t ws_size,
                              hipStream_t stream) {
    const int*   idx = (const int*)  d_in[0];
    const float* tok = (const float*)d_in[1];
    const float* pos = (const float*)d_in[2];
    const float* Wq  = (const float*)d_in[3];
    const float* bq  = (const float*)d_in[4];
    const float* Wk  = (const float*)d_in[5];
    const float* bk  = (const float*)d_in[6];
    const float* Wv  = (const float*)d_in[7];
    const float* bv  = (const float*)d_in[8];
    const float* Wo  = (const float*)d_in[9];
    const float* bo  = (const float*)d_in[10];
    const float* W1  = (const float*)d_in[11];
    const float* b1  = (const float*)d_in[12];
    const float* W2  = (const float*)d_in[13];
    const float* b2  = (const float*)d_in[14];
    const float* nw  = (const float*)d_in[15];
    const float* fnw = (const float*)d_in[16];
    const float* Wf  = (const float*)d_in[17];
    const float* bf  = (const float*)d_in[18];
    float* out = (float*)d_out;

    const size_t SZ   = (size_t)BT * DMODEL;    // 4M
    const size_t HSZF = (size_t)BT * DFF;       // 16M

    char* w = (char*)d_ws;
    auto alloc = [&](size_t bytes) {
        char* p = w;
        w += (bytes + 255) & ~(size_t)255;
        return p;
    };
    float* x    = (float*)alloc(SZ * 4);
    float* xo   = (float*)alloc(SZ * 4);
    bf16*  xnp  = (bf16*) alloc(SZ * 2 * 3);
    float* qkv  = (float*)alloc((size_t)BT * QLD * 4);
    bf16*  aop  = (bf16*) alloc(SZ * 2 * 3);
    bf16*  hbp  = (bf16*) alloc(HSZF * 2 * 3);                // ffn hidden planes
    char*  wreg = alloc(132ull * 1024 * 1024);
    bf16*  qkvTp = (bf16*)wreg;                               // 3 x 3072x1024
    bf16*  woTp  = qkvTp + 3ull * QLD * DMODEL;               // 3 x 1024x1024
    bf16*  w1Tp  = woTp  + 3ull * DMODEL * DMODEL;            // 3 x 4096x1024
    bf16*  w2Tp  = w1Tp  + 3ull * DFF * DMODEL;               // 3 x 1024x4096
    bf16*  wfp   = (bf16*)wreg;                               // 2 x 32000x1024
    float* catb  = (float*)alloc((size_t)NLAYER * QLD * 4);

    cat_bias<<<(NLAYER * QLD) / 256, 256, 0, stream>>>(bq, bk, bv, catb);
    embed_kernel<<<BT, 256, 0, stream>>>(idx, tok, pos, x);

    for (int l = 0; l < NLAYER; ++l) {
        const float* nwl = nw + (size_t)l * DMODEL;
        const float* catbl = catb + (size_t)l * QLD;
        const float* bol = bo + (size_t)l * DMODEL;
        const float* b1l = b1 + (size_t)l * DFF;
        const float* b2l = b2 + (size_t)l * DMODEL;

        // split this layer's weights into transposed bf16 planes
        {
            long izs = (long)DMODEL * HSZ;
            long ozi = (long)HSZ * DMODEL;
            size_t ps = (size_t)QLD * DMODEL;
            dim3 g(HSZ / 32, DMODEL / 32, NHEAD);
            const float* Wql = Wq + (size_t)l * NHEAD * DMODEL * HSZ;
            const float* Wkl = Wk + (size_t)l * NHEAD * DMODEL * HSZ;
            const float* Wvl = Wv + (size_t)l * NHEAD * DMODEL * HSZ;
            transpose_split<<<g, 256, 0, stream>>>(Wql, qkvTp,                 ps, 3, DMODEL, HSZ, izs, ozi);
            transpose_split<<<g, 256, 0, stream>>>(Wkl, qkvTp + 1024ul * 1024, ps, 3, DMODEL, HSZ, izs, ozi);
            transpose_split<<<g, 256, 0, stream>>>(Wvl, qkvTp + 2048ul * 1024, ps, 3, DMODEL, HSZ, izs, ozi);
            transpose_split<<<dim3(DMODEL / 32, DMODEL / 32, 1), 256, 0, stream>>>(
                Wo + (size_t)l * DMODEL * DMODEL, woTp, (size_t)DMODEL * DMODEL, 3, DMODEL, DMODEL, 0, 0);
            transpose_split<<<dim3(DFF / 32, DMODEL / 32, 1), 256, 0, stream>>>(
                W1 + (size_t)l * DMODEL * DFF, w1Tp, (size_t)DFF * DMODEL, 3, DMODEL, DFF, 0, 0);
            transpose_split<<<dim3(DMODEL / 32, DFF / 32, 1), 256, 0, stream>>>(
                W2 + (size_t)l * DMODEL * DFF, w2Tp, (size_t)DMODEL * DFF, 3, DFF, DMODEL, 0, 0);
        }

        auto attn = [&](const float* resid, float* outp, int causal) {
            gemm_wide<6, false, false><<<dim3((BT / 256) * (QLD / 128)), 512, 0, stream>>>(
                xnp, SZ, qkvTp, (size_t)QLD * DMODEL, catbl, nullptr,
                qkv, nullptr, 0, QLD, DMODEL);
            if (causal)
                attn_fused<1><<<dim3(T_SEQ / 64, BATCH * NHEAD), 64, 0, stream>>>(qkv, aop, SZ);
            else
                attn_fused<0><<<dim3(T_SEQ / 64, BATCH * NHEAD), 64, 0, stream>>>(qkv, aop, SZ);
            gemm_nar<6, false><<<dim3((BT / 128) * (DMODEL / 128)), 512, 0, stream>>>(
                aop, SZ, woTp, (size_t)DMODEL * DMODEL, bol, resid,
                outp, DMODEL, DMODEL);
        };

        // x_out1 = x + attn(rms(x), unmasked)
        rms_split<<<BT, 256, 0, stream>>>(x, nwl, xnp, SZ);
        attn(x, xo, 0);
        // x_out2 = x + ffn(rms(x_out1))      (residual from ORIGINAL x)
        rms_split<<<BT, 256, 0, stream>>>(xo, nwl, xnp, SZ);
        gemm_wide<6, true, true><<<dim3((BT / 256) * (DFF / 128)), 512, 0, stream>>>(
            xnp, SZ, w1Tp, (size_t)DFF * DMODEL, b1l, nullptr,
            nullptr, hbp, HSZF, DFF, DMODEL);
        gemm_nar<6, false><<<dim3((BT / 128) * (DMODEL / 128)), 512, 0, stream>>>(
            hbp, HSZF, w2Tp, (size_t)DMODEL * DFF, b2l, x,
            xo, DMODEL, DFF);
        // x = x_out2 + attn(rms(x_out2), masked)
        rms_split<<<BT, 256, 0, stream>>>(xo, nwl, xnp, SZ);
        attn(xo, x, 1);
    }

    // final: logits = rms(x, fnw) @ Wf + bf   (3-pass split, 2 planes, NARROW)
    rms_split<<<BT, 256, 0, stream>>>(x, fnw, xnp, SZ);
    transpose_split<<<dim3(VOCAB / 32, DMODEL / 32, 1), 256, 0, stream>>>(
        Wf, wfp, (size_t)VOCAB * DMODEL, 2, DMODEL, VOCAB, 0, 0);
    gemm_nar<3, false><<<dim3((BT / 128) * (VOCAB / 128)), 512, 0, stream>>>(
        xnp, SZ, wfp, (size_t)VOCAB * DMODEL, bf, nullptr,
        out, VOCAB, DMODEL);
}

// Round 9
// 11087.514 us; speedup vs baseline: 1.2778x; 1.2778x over previous
//
#include <hip/hip_runtime.h>
#include <hip/hip_bf16.h>
#include <cstdint>
#include <cstddef>

#define T_SEQ   512
#define BATCH   8
#define BT      4096
#define DMODEL  1024
#define NHEAD   16
#define HSZ     64
#define NLAYER  8
#define DFF     4096
#define VOCAB   32000
#define EPS     1e-6f
#define NEG_SLOPE 0.1f
#define QLD     3072    // fused qkv row stride

typedef __attribute__((ext_vector_type(8))) short short8;
typedef __attribute__((ext_vector_type(4))) float f32x4;
typedef __hip_bfloat16 bf16;

#define AS1 __attribute__((address_space(1)))
#define AS3 __attribute__((address_space(3)))

// counted-vmcnt wait fused with barrier: the N newest vmem ops stay in flight.
#define WAIT_BAR(N) asm volatile("s_waitcnt vmcnt(" #N ")\ns_barrier" ::: "memory")
#define LGKM_BAR()  asm volatile("s_waitcnt lgkmcnt(0)\ns_barrier" ::: "memory")

// ---------------------------------------------------------------------------
__global__ void embed_kernel(const int* __restrict__ idx,
                             const float* __restrict__ tok,
                             const float* __restrict__ pos,
                             float* __restrict__ x) {
    int bt  = blockIdx.x;
    int tid = threadIdx.x;
    int token = idx[bt];
    int t = bt & (T_SEQ - 1);
    float4 a = reinterpret_cast<const float4*>(tok + (size_t)token * DMODEL)[tid];
    float4 p = reinterpret_cast<const float4*>(pos + (size_t)t * DMODEL)[tid];
    reinterpret_cast<float4*>(x + (size_t)bt * DMODEL)[tid] =
        make_float4(a.x + p.x, a.y + p.y, a.z + p.z, a.w + p.w);
}

// ---------------------------------------------------------------------------
__device__ __forceinline__ void split3v(float v, bf16& h, bf16& m, bf16& l) {
    h = __float2bfloat16(v);
    float r1 = v - __bfloat162float(h);
    m = __float2bfloat16(r1);
    float r2 = r1 - __bfloat162float(m);
    l = __float2bfloat16(r2);
}

// ---------------------------------------------------------------------------
__global__ void rms_split(const float* __restrict__ x,
                          const float* __restrict__ w,
                          bf16* __restrict__ out, size_t planeStride) {
    int row = blockIdx.x;
    int tid = threadIdx.x;
    float4 v = reinterpret_cast<const float4*>(x + (size_t)row * DMODEL)[tid];
    float ss = v.x * v.x + v.y * v.y + v.z * v.z + v.w * v.w;
#pragma unroll
    for (int off = 32; off > 0; off >>= 1) ss += __shfl_xor(ss, off);
    __shared__ float wsum[4];
    if ((tid & 63) == 0) wsum[tid >> 6] = ss;
    __syncthreads();
    float tot = wsum[0] + wsum[1] + wsum[2] + wsum[3];
    float scale = rsqrtf(tot * (1.0f / DMODEL) + EPS);
    float4 wv = reinterpret_cast<const float4*>(w)[tid];
    float o[4] = {v.x * scale * wv.x, v.y * scale * wv.y,
                  v.z * scale * wv.z, v.w * scale * wv.w};
    size_t base = (size_t)row * DMODEL + tid * 4;
#pragma unroll
    for (int j = 0; j < 4; ++j) {
        bf16 h, m, l;
        split3v(o[j], h, m, l);
        out[base + j] = h;
        out[planeStride + base + j] = m;
        out[2 * planeStride + base + j] = l;
    }
}

// ---------------------------------------------------------------------------
__global__ __launch_bounds__(256)
void transpose_split(const float* __restrict__ in, bf16* __restrict__ out,
                     size_t planeStride, int nPlanes, int R, int C,
                     long izs, long ozi) {
    int z = blockIdx.z;
    in  += (size_t)z * izs;
    out += (size_t)z * ozi;
    __shared__ float tile[32][33];
    int r0 = blockIdx.y << 5, c0 = blockIdx.x << 5;
    int tx = threadIdx.x & 31, ty = threadIdx.x >> 5;
#pragma unroll
    for (int i = 0; i < 4; ++i) {
        int r = ty + (i << 3);
        tile[r][tx] = in[(size_t)(r0 + r) * C + c0 + tx];
    }
    __syncthreads();
#pragma unroll
    for (int i = 0; i < 4; ++i) {
        int c = ty + (i << 3);
        float v = tile[tx][c];
        size_t o = (size_t)(c0 + c) * R + r0 + tx;
        bf16 h = __float2bfloat16(v);
        out[o] = h;
        if (nPlanes > 1) {
            float r1 = v - __bfloat162float(h);
            bf16 m = __float2bfloat16(r1);
            out[planeStride + o] = m;
            if (nPlanes > 2) {
                float r2 = r1 - __bfloat162float(m);
                out[2 * planeStride + o] = __float2bfloat16(r2);
            }
        }
    }
}

// concat per-layer qkv bias into (L, 3072) f32
__global__ void cat_bias(const float* __restrict__ bq, const float* __restrict__ bk,
                         const float* __restrict__ bv, float* __restrict__ cb) {
    int i = blockIdx.x * 256 + threadIdx.x;
    int l = i / QLD, r = i - l * QLD;
    const float* src = (r < 1024) ? bq : ((r < 2048) ? bk : bv);
    cb[i] = src[l * 1024 + (r & 1023)];
}

// ---------------------------------------------------------------------------
// B-single-buffer merged-pass split GEMM (128x128 tile, 512 thr / 8 waves,
// wave grid 2m x 4n, 64x32 out/wave, acc 4x2).
// Key structural point: fragments are copied LDS->regs at step top; after
// LGKM_BAR the LDS is dead, so only A needs a double buffer (staged at step
// top, counted WAIT_BAR) while B(t+1) overwrites Bs mid-step under the MFMA
// block (~1800 cyc >> HBM latency). LDS: NP6 72KB (2 blk/CU), NP3 48KB (3).
// vmcnt bookkeeping (FIFO, m135): top of step t outstanding = A(t):NPA +
// B(t):NPB; issue A(t+1):NPA; WAIT_BAR(NPA) drains A(t),B(t) exactly.
template <int NP, bool LRELU, bool SPLITOUT>
__global__ __launch_bounds__(512, 2)
void gemm_bs(const bf16* __restrict__ A, size_t aPS,
             const bf16* __restrict__ Bt, size_t bPS,
             const float* __restrict__ bias,
             const float* __restrict__ resid,
             float* __restrict__ C, bf16* __restrict__ Cp, size_t cPS,
             int N, int K) {
    constexpr int NPA = (NP == 6) ? 3 : 2;
    constexpr int NPB = (NP == 6) ? 3 : 2;
    constexpr int PA[6] = {1, 0, 2, 0, 1, 0};   // mm,hl,lh,hm,mh,hh
    constexpr int PB[6] = {1, 2, 0, 1, 0, 0};
    __shared__ bf16 As[2][NPA * 4096];   // 128 rows x 32 k per plane, dbuf
    __shared__ bf16 Bs[NPB * 4096];      // single buffer

    int chunk = gridDim.x >> 3;
    int bid = blockIdx.x;
    int sw = (bid & 7) * chunk + (bid >> 3);
    int m0 = (sw & 31) << 7;
    int n0 = (sw >> 5) << 7;

    const int tid  = threadIdx.x;
    const int lane = tid & 63;
    const int wid  = tid >> 6;

    // staging: thread t -> row t>>2, 16B k-slot (t&3), XOR-preswizzled source
    const int ssk = (((tid & 3) ^ ((tid >> 3) & 3)) << 3);
    const size_t offA = (size_t)(m0 + (tid >> 2)) * K + ssk;
    const size_t offB = (size_t)(n0 + (tid >> 2)) * K + ssk;
    const int ldst = wid * 512;          // wave-uniform LDS elem base

    f32x4 acc[4][2];
#pragma unroll
    for (int i = 0; i < 4; ++i)
#pragma unroll
        for (int j = 0; j < 2; ++j) acc[i][j] = (f32x4){0.f, 0.f, 0.f, 0.f};

    const int wr = wid >> 2, wc = wid & 3;
    const int fm = lane & 15;
    const int rslot = (((lane >> 4) ^ ((lane >> 1) & 3)) & 3) << 3;
    int foffA[4], foffB[2];
#pragma unroll
    for (int i = 0; i < 4; ++i) foffA[i] = (wr * 64 + i * 16 + fm) * 32 + rslot;
#pragma unroll
    for (int j = 0; j < 2; ++j) foffB[j] = (wc * 32 + j * 16 + fm) * 32 + rslot;

    auto STAGE_A = [&](int buf, int k0) {
#pragma unroll
        for (int pp = 0; pp < NPA; ++pp)
            __builtin_amdgcn_global_load_lds(
                (const AS1 void*)(A + pp * aPS + offA + k0),
                (AS3 void*)(&As[buf][pp * 4096 + ldst]), 16, 0, 0);
    };
    auto STAGE_B = [&](int k0) {
#pragma unroll
        for (int pp = 0; pp < NPB; ++pp)
            __builtin_amdgcn_global_load_lds(
                (const AS1 void*)(Bt + pp * bPS + offB + k0),
                (AS3 void*)(&Bs[pp * 4096 + ldst]), 16, 0, 0);
    };

    const int nt = K >> 5;
    STAGE_A(0, 0);
    STAGE_B(0);
    int cur = 0;
    for (int t = 0; t < nt; ++t) {
        if (t + 1 < nt) {
            STAGE_A(cur ^ 1, (t + 1) << 5);
            if constexpr (NP == 6) WAIT_BAR(3); else WAIT_BAR(2);
        } else {
            WAIT_BAR(0);
        }

        short8 af[NPA][4], bfr[NPB][2];
#pragma unroll
        for (int pp = 0; pp < NPA; ++pp)
#pragma unroll
            for (int i = 0; i < 4; ++i)
                af[pp][i] = *(const short8*)(&As[cur][pp * 4096 + foffA[i]]);
#pragma unroll
        for (int pp = 0; pp < NPB; ++pp)
#pragma unroll
            for (int j = 0; j < 2; ++j)
                bfr[pp][j] = *(const short8*)(&Bs[pp * 4096 + foffB[j]]);
        LGKM_BAR();                         // frags in regs; Bs now dead
        if (t + 1 < nt) STAGE_B((t + 1) << 5);   // overwrite Bs under MFMA

#pragma unroll
        for (int pp = 6 - NP; pp < 6; ++pp)
#pragma unroll
            for (int i = 0; i < 4; ++i)
#pragma unroll
                for (int j = 0; j < 2; ++j)
                    acc[i][j] = __builtin_amdgcn_mfma_f32_16x16x32_bf16(
                        af[PA[pp]][i], bfr[PB[pp]][j], acc[i][j], 0, 0, 0);
        cur ^= 1;
    }

    // epilogue: C/D layout col = lane&15, row = (lane>>4)*4 + rr
#pragma unroll
    for (int i = 0; i < 4; ++i) {
        int mbase = m0 + wr * 64 + i * 16 + ((lane >> 4) << 2);
#pragma unroll
        for (int j = 0; j < 2; ++j) {
            int n = n0 + wc * 32 + j * 16 + fm;
            float bv = bias[n];
#pragma unroll
            for (int rr = 0; rr < 4; ++rr) {
                int m = mbase + rr;
                float v = acc[i][j][rr] + bv;
                if (LRELU) v = (v >= 0.f) ? v : NEG_SLOPE * v;
                size_t o = (size_t)m * N + n;
                if (SPLITOUT) {
                    bf16 h, mm, ll;
                    split3v(v, h, mm, ll);
                    Cp[o] = h;
                    Cp[cPS + o] = mm;
                    Cp[2 * cPS + o] = ll;
                } else {
                    if (resid) v += resid[o];
                    C[o] = v;
                }
            }
        }
    }
}

// ---------------------------------------------------------------------------
// Fused attention (f32 vector, 256 thr): per block one 64-row q-tile of one
// (b,h). Proven r5/r7 structure.
template <int CAUSAL>
__global__ __launch_bounds__(256)
void attn_fused(const float* __restrict__ qkv, bf16* __restrict__ outp,
                size_t planeStride) {
    int bh = blockIdx.y;
    int b = bh >> 4, h = bh & 15;
    int t0 = blockIdx.x << 6;
    __shared__ float Qst[64][68];
    __shared__ float KPs[64][68];
    __shared__ float Vs[64][68];
    const int tid = threadIdx.x;
    const int tx = tid & 15, ty = tid >> 4;
    const int lr = tid >> 4, le = (tid & 15) << 2;

    const float* qb = qkv + (size_t)(b * T_SEQ + t0) * QLD + h * HSZ;
#pragma unroll
    for (int r = 0; r < 4; ++r) {
        int row = lr + (r << 4);
        float4 qv = *reinterpret_cast<const float4*>(qb + (size_t)row * QLD + le);
        Qst[le + 0][row] = qv.x;
        Qst[le + 1][row] = qv.y;
        Qst[le + 2][row] = qv.z;
        Qst[le + 3][row] = qv.w;
    }

    float o[4][4] = {};
    float mrow[4] = {-INFINITY, -INFINITY, -INFINITY, -INFINITY};
    float lrow[4] = {};

    const int NT = CAUSAL ? (blockIdx.x + 1) : (T_SEQ / 64);
    for (int st = 0; st < NT; ++st) {
        int s0 = st << 6;
        const float* kb = qkv + 1024 + (size_t)(b * T_SEQ + s0) * QLD + h * HSZ;
        const float* vb = qkv + 2048 + (size_t)(b * T_SEQ + s0) * QLD + h * HSZ;
#pragma unroll
        for (int r = 0; r < 4; ++r) {
            int row = lr + (r << 4);
            float4 kv = *reinterpret_cast<const float4*>(kb + (size_t)row * QLD + le);
            KPs[le + 0][row] = kv.x;
            KPs[le + 1][row] = kv.y;
            KPs[le + 2][row] = kv.z;
            KPs[le + 3][row] = kv.w;
            float4 vv = *reinterpret_cast<const float4*>(vb + (size_t)row * QLD + le);
            *reinterpret_cast<float4*>(&Vs[row][le]) = vv;
        }
        __syncthreads();

        float s[4][4] = {};
        for (int e = 0; e < 64; ++e) {
            float4 a = *reinterpret_cast<const float4*>(&Qst[e][ty << 2]);
            float4 bb = *reinterpret_cast<const float4*>(&KPs[e][tx << 2]);
            float av[4] = {a.x, a.y, a.z, a.w};
            float bv[4] = {bb.x, bb.y, bb.z, bb.w};
#pragma unroll
            for (int i = 0; i < 4; ++i)
#pragma unroll
                for (int j = 0; j < 4; ++j) s[i][j] += av[i] * bv[j];
        }
#pragma unroll
        for (int i = 0; i < 4; ++i)
#pragma unroll
            for (int j = 0; j < 4; ++j) {
                float v = 8.0f * s[i][j];
                if (CAUSAL) {
                    int scol = s0 + (tx << 2) + j;
                    int trow = t0 + (ty << 2) + i;
                    if (scol > trow) v = -INFINITY;
                }
                s[i][j] = v;
            }

#pragma unroll
        for (int i = 0; i < 4; ++i) {
            float rmax = fmaxf(fmaxf(s[i][0], s[i][1]), fmaxf(s[i][2], s[i][3]));
#pragma unroll
            for (int msk = 1; msk < 16; msk <<= 1)
                rmax = fmaxf(rmax, __shfl_xor(rmax, msk));
            float mn = fmaxf(mrow[i], rmax);
            float fsc = __expf(mrow[i] - mn);
            float rs = 0.f;
#pragma unroll
            for (int j = 0; j < 4; ++j) {
                float pv = __expf(s[i][j] - mn);
                s[i][j] = pv;
                rs += pv;
            }
#pragma unroll
            for (int msk = 1; msk < 16; msk <<= 1) rs += __shfl_xor(rs, msk);
            lrow[i] = lrow[i] * fsc + rs;
            mrow[i] = mn;
#pragma unroll
            for (int j = 0; j < 4; ++j) o[i][j] *= fsc;
        }
        __syncthreads();

#pragma unroll
        for (int i = 0; i < 4; ++i)
#pragma unroll
            for (int j = 0; j < 4; ++j)
                KPs[(tx << 2) + j][(ty << 2) + i] = s[i][j];
        __syncthreads();

        for (int kk = 0; kk < 64; ++kk) {
            float4 a = *reinterpret_cast<const float4*>(&KPs[kk][ty << 2]);
            float4 bb = *reinterpret_cast<const float4*>(&Vs[kk][tx << 2]);
            float av[4] = {a.x, a.y, a.z, a.w};
            float bv[4] = {bb.x, bb.y, bb.z, bb.w};
#pragma unroll
            for (int i = 0; i < 4; ++i)
#pragma unroll
                for (int j = 0; j < 4; ++j) o[i][j] += av[i] * bv[j];
        }
        __syncthreads();
    }

#pragma unroll
    for (int i = 0; i < 4; ++i) {
        float inv = 1.f / lrow[i];
        size_t orow = (size_t)(b * T_SEQ + t0 + (ty << 2) + i) * DMODEL
                      + h * HSZ + (tx << 2);
#pragma unroll
        for (int j = 0; j < 4; ++j) {
            bf16 h_, m_, l_;
            split3v(o[i][j] * inv, h_, m_, l_);
            outp[orow + j] = h_;
            outp[planeStride + orow + j] = m_;
            outp[2 * planeStride + orow + j] = l_;
        }
    }
}

// ---------------------------------------------------------------------------
extern "C" void kernel_launch(void* const* d_in, const int* in_sizes, int n_in,
                              void* d_out, int out_size, void* d_ws, size_t ws_size,
                              hipStream_t stream) {
    const int*   idx = (const int*)  d_in[0];
    const float* tok = (const float*)d_in[1];
    const float* pos = (const float*)d_in[2];
    const float* Wq  = (const float*)d_in[3];
    const float* bq  = (const float*)d_in[4];
    const float* Wk  = (const float*)d_in[5];
    const float* bk  = (const float*)d_in[6];
    const float* Wv  = (const float*)d_in[7];
    const float* bv  = (const float*)d_in[8];
    const float* Wo  = (const float*)d_in[9];
    const float* bo  = (const float*)d_in[10];
    const float* W1  = (const float*)d_in[11];
    const float* b1  = (const float*)d_in[12];
    const float* W2  = (const float*)d_in[13];
    const float* b2  = (const float*)d_in[14];
    const float* nw  = (const float*)d_in[15];
    const float* fnw = (const float*)d_in[16];
    const float* Wf  = (const float*)d_in[17];
    const float* bf  = (const float*)d_in[18];
    float* out = (float*)d_out;

    const size_t SZ   = (size_t)BT * DMODEL;    // 4M
    const size_t HSZF = (size_t)BT * DFF;       // 16M

    char* w = (char*)d_ws;
    auto alloc = [&](size_t bytes) {
        char* p = w;
        w += (bytes + 255) & ~(size_t)255;
        return p;
    };
    float* x    = (float*)alloc(SZ * 4);
    float* xo   = (float*)alloc(SZ * 4);
    bf16*  xnp  = (bf16*) alloc(SZ * 2 * 3);
    float* qkv  = (float*)alloc((size_t)BT * QLD * 4);
    bf16*  aop  = (bf16*) alloc(SZ * 2 * 3);
    bf16*  hbp  = (bf16*) alloc(HSZF * 2 * 3);                // ffn hidden planes
    char*  wreg = alloc(132ull * 1024 * 1024);
    bf16*  qkvTp = (bf16*)wreg;                               // 3 x 3072x1024
    bf16*  woTp  = qkvTp + 3ull * QLD * DMODEL;               // 3 x 1024x1024
    bf16*  w1Tp  = woTp  + 3ull * DMODEL * DMODEL;            // 3 x 4096x1024
    bf16*  w2Tp  = w1Tp  + 3ull * DFF * DMODEL;               // 3 x 1024x4096
    bf16*  wfp   = (bf16*)wreg;                               // 2 x 32000x1024
    float* catb  = (float*)alloc((size_t)NLAYER * QLD * 4);

    cat_bias<<<(NLAYER * QLD) / 256, 256, 0, stream>>>(bq, bk, bv, catb);
    embed_kernel<<<BT, 256, 0, stream>>>(idx, tok, pos, x);

    for (int l = 0; l < NLAYER; ++l) {
        const float* nwl = nw + (size_t)l * DMODEL;
        const float* catbl = catb + (size_t)l * QLD;
        const float* bol = bo + (size_t)l * DMODEL;
        const float* b1l = b1 + (size_t)l * DFF;
        const float* b2l = b2 + (size_t)l * DMODEL;

        // split this layer's weights into transposed bf16 planes
        {
            long izs = (long)DMODEL * HSZ;
            long ozi = (long)HSZ * DMODEL;
            size_t ps = (size_t)QLD * DMODEL;
            dim3 g(HSZ / 32, DMODEL / 32, NHEAD);
            const float* Wql = Wq + (size_t)l * NHEAD * DMODEL * HSZ;
            const float* Wkl = Wk + (size_t)l * NHEAD * DMODEL * HSZ;
            const float* Wvl = Wv + (size_t)l * NHEAD * DMODEL * HSZ;
            transpose_split<<<g, 256, 0, stream>>>(Wql, qkvTp,                 ps, 3, DMODEL, HSZ, izs, ozi);
            transpose_split<<<g, 256, 0, stream>>>(Wkl, qkvTp + 1024ul * 1024, ps, 3, DMODEL, HSZ, izs, ozi);
            transpose_split<<<g, 256, 0, stream>>>(Wvl, qkvTp + 2048ul * 1024, ps, 3, DMODEL, HSZ, izs, ozi);
            transpose_split<<<dim3(DMODEL / 32, DMODEL / 32, 1), 256, 0, stream>>>(
                Wo + (size_t)l * DMODEL * DMODEL, woTp, (size_t)DMODEL * DMODEL, 3, DMODEL, DMODEL, 0, 0);
            transpose_split<<<dim3(DFF / 32, DMODEL / 32, 1), 256, 0, stream>>>(
                W1 + (size_t)l * DMODEL * DFF, w1Tp, (size_t)DFF * DMODEL, 3, DMODEL, DFF, 0, 0);
            transpose_split<<<dim3(DMODEL / 32, DFF / 32, 1), 256, 0, stream>>>(
                W2 + (size_t)l * DMODEL * DFF, w2Tp, (size_t)DMODEL * DFF, 3, DFF, DMODEL, 0, 0);
        }

        auto attn = [&](const float* resid, float* outp, int causal) {
            gemm_bs<6, false, false><<<dim3((BT / 128) * (QLD / 128)), 512, 0, stream>>>(
                xnp, SZ, qkvTp, (size_t)QLD * DMODEL, catbl, nullptr,
                qkv, nullptr, 0, QLD, DMODEL);
            if (causal)
                attn_fused<1><<<dim3(T_SEQ / 64, BATCH * NHEAD), 256, 0, stream>>>(qkv, aop, SZ);
            else
                attn_fused<0><<<dim3(T_SEQ / 64, BATCH * NHEAD), 256, 0, stream>>>(qkv, aop, SZ);
            gemm_bs<6, false, false><<<dim3((BT / 128) * (DMODEL / 128)), 512, 0, stream>>>(
                aop, SZ, woTp, (size_t)DMODEL * DMODEL, bol, resid,
                outp, nullptr, 0, DMODEL, DMODEL);
        };

        // x_out1 = x + attn(rms(x), unmasked)
        rms_split<<<BT, 256, 0, stream>>>(x, nwl, xnp, SZ);
        attn(x, xo, 0);
        // x_out2 = x + ffn(rms(x_out1))      (residual from ORIGINAL x)
        rms_split<<<BT, 256, 0, stream>>>(xo, nwl, xnp, SZ);
        gemm_bs<6, true, true><<<dim3((BT / 128) * (DFF / 128)), 512, 0, stream>>>(
            xnp, SZ, w1Tp, (size_t)DFF * DMODEL, b1l, nullptr,
            nullptr, hbp, HSZF, DFF, DMODEL);
        gemm_bs<6, false, false><<<dim3((BT / 128) * (DMODEL / 128)), 512, 0, stream>>>(
            hbp, HSZF, w2Tp, (size_t)DMODEL * DFF, b2l, x,
            xo, nullptr, 0, DMODEL, DFF);
        // x = x_out2 + attn(rms(x_out2), masked)
        rms_split<<<BT, 256, 0, stream>>>(xo, nwl, xnp, SZ);
        attn(xo, x, 1);
    }

    // final: logits = rms(x, fnw) @ Wf + bf   (3-pass split, 2 planes)
    rms_split<<<BT, 256, 0, stream>>>(x, fnw, xnp, SZ);
    transpose_split<<<dim3(VOCAB / 32, DMODEL / 32, 1), 256, 0, stream>>>(
        Wf, wfp, (size_t)VOCAB * DMODEL, 2, DMODEL, VOCAB, 0, 0);
    gemm_bs<3, false, false><<<dim3((BT / 128) * (VOCAB / 128)), 512, 0, stream>>>(
        xnp, SZ, wfp, (size_t)VOCAB * DMODEL, bf, nullptr,
        out, nullptr, 0, VOCAB, DMODEL);
}

// Round 11
// 8691.750 us; speedup vs baseline: 1.6300x; 1.2756x over previous
//
#include <hip/hip_runtime.h>
#include <hip/hip_bf16.h>
#include <cstdint>
#include <cstddef>

#define T_SEQ   512
#define BATCH   8
#define BT      4096
#define DMODEL  1024
#define NHEAD   16
#define HSZ     64
#define NLAYER  8
#define DFF     4096
#define VOCAB   32000
#define EPS     1e-6f
#define NEG_SLOPE 0.1f
#define QLD     3072    // fused qkv row stride
#define MSCALE  2048.0f
#define MINV    (1.0f / 2048.0f)

typedef _Float16 f16;
typedef __attribute__((ext_vector_type(8))) _Float16 half8;
typedef __attribute__((ext_vector_type(4))) float f32x4;

#define AS1 __attribute__((address_space(1)))
#define AS3 __attribute__((address_space(3)))

// counted-vmcnt wait fused with barrier: the N newest vmem ops stay in flight.
#define WAIT_BAR(N) asm volatile("s_waitcnt vmcnt(" #N ")\ns_barrier" ::: "memory")
#define LGKM_BAR()  asm volatile("s_waitcnt lgkmcnt(0)\ns_barrier" ::: "memory")

// ---------------------------------------------------------------------------
__global__ void embed_kernel(const int* __restrict__ idx,
                             const float* __restrict__ tok,
                             const float* __restrict__ pos,
                             float* __restrict__ x) {
    int bt  = blockIdx.x;
    int tid = threadIdx.x;
    int token = idx[bt];
    int t = bt & (T_SEQ - 1);
    float4 a = reinterpret_cast<const float4*>(tok + (size_t)token * DMODEL)[tid];
    float4 p = reinterpret_cast<const float4*>(pos + (size_t)t * DMODEL)[tid];
    reinterpret_cast<float4*>(x + (size_t)bt * DMODEL)[tid] =
        make_float4(a.x + p.x, a.y + p.y, a.z + p.z, a.w + p.w);
}

// ---------------------------------------------------------------------------
// f16 2-plane split with scaled low plane: x ~= h + m/2048, residual ~2^-23|x|.
// h flushed to zero in the denormal range so MFMA-vs-convert flush behavior
// cannot desync the planes (m absorbs the value).
__device__ __forceinline__ void split2h(float v, f16& h, f16& m) {
    f16 hh = (f16)v;
    float hf = (float)hh;
    if (fabsf(hf) < 6.103515625e-05f) { hh = (f16)0.0f; hf = 0.0f; }
    h = hh;
    m = (f16)((v - hf) * MSCALE);
}

// ---------------------------------------------------------------------------
// rmsnorm f32 -> 2 f16 planes (h, m')
__global__ void rms_split(const float* __restrict__ x,
                          const float* __restrict__ w,
                          f16* __restrict__ out, size_t planeStride) {
    int row = blockIdx.x;
    int tid = threadIdx.x;
    float4 v = reinterpret_cast<const float4*>(x + (size_t)row * DMODEL)[tid];
    float ss = v.x * v.x + v.y * v.y + v.z * v.z + v.w * v.w;
#pragma unroll
    for (int off = 32; off > 0; off >>= 1) ss += __shfl_xor(ss, off);
    __shared__ float wsum[4];
    if ((tid & 63) == 0) wsum[tid >> 6] = ss;
    __syncthreads();
    float tot = wsum[0] + wsum[1] + wsum[2] + wsum[3];
    float scale = rsqrtf(tot * (1.0f / DMODEL) + EPS);
    float4 wv = reinterpret_cast<const float4*>(w)[tid];
    float o[4] = {v.x * scale * wv.x, v.y * scale * wv.y,
                  v.z * scale * wv.z, v.w * scale * wv.w};
    size_t base = (size_t)row * DMODEL + tid * 4;
#pragma unroll
    for (int j = 0; j < 4; ++j) {
        f16 h, m;
        split2h(o[j], h, m);
        out[base + j] = h;
        out[planeStride + base + j] = m;
    }
}

// ---------------------------------------------------------------------------
// Tiled transpose + split: in (R,C) f32 -> out (C,R) f16 x 2 planes
__global__ __launch_bounds__(256)
void transpose_split(const float* __restrict__ in, f16* __restrict__ out,
                     size_t planeStride, int R, int C,
                     long izs, long ozi) {
    int z = blockIdx.z;
    in  += (size_t)z * izs;
    out += (size_t)z * ozi;
    __shared__ float tile[32][33];
    int r0 = blockIdx.y << 5, c0 = blockIdx.x << 5;
    int tx = threadIdx.x & 31, ty = threadIdx.x >> 5;
#pragma unroll
    for (int i = 0; i < 4; ++i) {
        int r = ty + (i << 3);
        tile[r][tx] = in[(size_t)(r0 + r) * C + c0 + tx];
    }
    __syncthreads();
#pragma unroll
    for (int i = 0; i < 4; ++i) {
        int c = ty + (i << 3);
        float v = tile[tx][c];
        size_t o = (size_t)(c0 + c) * R + r0 + tx;
        f16 h, m;
        split2h(v, h, m);
        out[o] = h;
        out[planeStride + o] = m;
    }
}

// concat per-layer qkv bias into (L, 3072) f32
__global__ void cat_bias(const float* __restrict__ bq, const float* __restrict__ bk,
                         const float* __restrict__ bv, float* __restrict__ cb) {
    int i = blockIdx.x * 256 + threadIdx.x;
    int l = i / QLD, r = i - l * QLD;
    const float* src = (r < 1024) ? bq : ((r < 2048) ? bk : bv);
    cb[i] = src[l * 1024 + (r & 1023)];
}

// ---------------------------------------------------------------------------
// f16 split-GEMM, 3 passes, 2 accumulators, B-single-buffer (r9 structure).
// C = (accH + accM/2048) where accH = Ah@Bh^T, accM = Am@Bh^T + Ah@Bm^T.
// Residual error ~2^-23: f32-grade. 128x128 tile, 512 thr / 8 waves (2m x 4n),
// 64x32 out/wave, acc 2 x 4x2. LDS = A dbuf 32KB + B single 16KB = 48KB.
// vmcnt (FIFO): top of step t outstanding = A(t):2 + B(t):2; issue A(t+1):2;
// WAIT_BAR(2) drains A(t),B(t) exactly, keeps A(t+1) in flight.
template <bool LRELU, bool SPLITOUT>
__global__ __launch_bounds__(512, 2)
void gemm_f16(const f16* __restrict__ A, size_t aPS,
              const f16* __restrict__ Bt, size_t bPS,
              const float* __restrict__ bias,
              const float* __restrict__ resid,
              float* __restrict__ C, f16* __restrict__ Cp, size_t cPS,
              int N, int K) {
    __shared__ f16 As[2][2 * 4096];   // 128 rows x 32 k per plane, dbuf
    __shared__ f16 Bs[2 * 4096];      // single buffer

    int chunk = gridDim.x >> 3;
    int bid = blockIdx.x;
    int sw = (bid & 7) * chunk + (bid >> 3);
    int m0 = (sw & 31) << 7;
    int n0 = (sw >> 5) << 7;

    const int tid  = threadIdx.x;
    const int lane = tid & 63;
    const int wid  = tid >> 6;

    // staging: thread t -> row t>>2, 16B k-slot (t&3), XOR-preswizzled source
    const int ssk = (((tid & 3) ^ ((tid >> 3) & 3)) << 3);
    const size_t offA = (size_t)(m0 + (tid >> 2)) * K + ssk;
    const size_t offB = (size_t)(n0 + (tid >> 2)) * K + ssk;
    const int ldst = wid * 512;          // wave-uniform LDS elem base

    f32x4 accH[4][2], accM[4][2];
#pragma unroll
    for (int i = 0; i < 4; ++i)
#pragma unroll
        for (int j = 0; j < 2; ++j) {
            accH[i][j] = (f32x4){0.f, 0.f, 0.f, 0.f};
            accM[i][j] = (f32x4){0.f, 0.f, 0.f, 0.f};
        }

    const int wr = wid >> 2, wc = wid & 3;
    const int fm = lane & 15;
    const int rslot = (((lane >> 4) ^ ((lane >> 1) & 3)) & 3) << 3;
    int foffA[4], foffB[2];
#pragma unroll
    for (int i = 0; i < 4; ++i) foffA[i] = (wr * 64 + i * 16 + fm) * 32 + rslot;
#pragma unroll
    for (int j = 0; j < 2; ++j) foffB[j] = (wc * 32 + j * 16 + fm) * 32 + rslot;

    auto STAGE_A = [&](int buf, int k0) {
#pragma unroll
        for (int pp = 0; pp < 2; ++pp)
            __builtin_amdgcn_global_load_lds(
                (const AS1 void*)(A + pp * aPS + offA + k0),
                (AS3 void*)(&As[buf][pp * 4096 + ldst]), 16, 0, 0);
    };
    auto STAGE_B = [&](int k0) {
#pragma unroll
        for (int pp = 0; pp < 2; ++pp)
            __builtin_amdgcn_global_load_lds(
                (const AS1 void*)(Bt + pp * bPS + offB + k0),
                (AS3 void*)(&Bs[pp * 4096 + ldst]), 16, 0, 0);
    };

    const int nt = K >> 5;
    STAGE_A(0, 0);
    STAGE_B(0);
    int cur = 0;
    for (int t = 0; t < nt; ++t) {
        if (t + 1 < nt) {
            STAGE_A(cur ^ 1, (t + 1) << 5);
            WAIT_BAR(2);
        } else {
            WAIT_BAR(0);
        }

        half8 af[2][4], bfr[2][2];
#pragma unroll
        for (int pp = 0; pp < 2; ++pp)
#pragma unroll
            for (int i = 0; i < 4; ++i)
                af[pp][i] = *(const half8*)(&As[cur][pp * 4096 + foffA[i]]);
#pragma unroll
        for (int pp = 0; pp < 2; ++pp)
#pragma unroll
            for (int j = 0; j < 2; ++j)
                bfr[pp][j] = *(const half8*)(&Bs[pp * 4096 + foffB[j]]);
        LGKM_BAR();                         // frags in regs; Bs now dead
        if (t + 1 < nt) STAGE_B((t + 1) << 5);   // overwrite Bs under MFMA

        // pass 1: Am @ Bh -> accM ; pass 2: Ah @ Bm -> accM ; pass 3: Ah @ Bh -> accH
#pragma unroll
        for (int i = 0; i < 4; ++i)
#pragma unroll
            for (int j = 0; j < 2; ++j)
                accM[i][j] = __builtin_amdgcn_mfma_f32_16x16x32_f16(
                    af[1][i], bfr[0][j], accM[i][j], 0, 0, 0);
#pragma unroll
        for (int i = 0; i < 4; ++i)
#pragma unroll
            for (int j = 0; j < 2; ++j)
                accM[i][j] = __builtin_amdgcn_mfma_f32_16x16x32_f16(
                    af[0][i], bfr[1][j], accM[i][j], 0, 0, 0);
#pragma unroll
        for (int i = 0; i < 4; ++i)
#pragma unroll
            for (int j = 0; j < 2; ++j)
                accH[i][j] = __builtin_amdgcn_mfma_f32_16x16x32_f16(
                    af[0][i], bfr[0][j], accH[i][j], 0, 0, 0);
        cur ^= 1;
    }

    // epilogue: C/D layout col = lane&15, row = (lane>>4)*4 + rr
#pragma unroll
    for (int i = 0; i < 4; ++i) {
        int mbase = m0 + wr * 64 + i * 16 + ((lane >> 4) << 2);
#pragma unroll
        for (int j = 0; j < 2; ++j) {
            int n = n0 + wc * 32 + j * 16 + fm;
            float bv = bias[n];
#pragma unroll
            for (int rr = 0; rr < 4; ++rr) {
                int m = mbase + rr;
                float v = accH[i][j][rr] + accM[i][j][rr] * MINV + bv;
                if (LRELU) v = (v >= 0.f) ? v : NEG_SLOPE * v;
                size_t o = (size_t)m * N + n;
                if (SPLITOUT) {
                    f16 h, mm;
                    split2h(v, h, mm);
                    Cp[o] = h;
                    Cp[cPS + o] = mm;
                } else {
                    if (resid) v += resid[o];
                    C[o] = v;
                }
            }
        }
    }
}

// ---------------------------------------------------------------------------
// Fused attention (f32 vector, 256 thr): per block one 64-row q-tile of one
// (b,h). Proven r5/r7/r9 structure; epilogue writes 2 f16 planes.
template <int CAUSAL>
__global__ __launch_bounds__(256)
void attn_fused(const float* __restrict__ qkv, f16* __restrict__ outp,
                size_t planeStride) {
    int bh = blockIdx.y;
    int b = bh >> 4, h = bh & 15;
    int t0 = blockIdx.x << 6;
    __shared__ float Qst[64][68];
    __shared__ float KPs[64][68];
    __shared__ float Vs[64][68];
    const int tid = threadIdx.x;
    const int tx = tid & 15, ty = tid >> 4;
    const int lr = tid >> 4, le = (tid & 15) << 2;

    const float* qb = qkv + (size_t)(b * T_SEQ + t0) * QLD + h * HSZ;
#pragma unroll
    for (int r = 0; r < 4; ++r) {
        int row = lr + (r << 4);
        float4 qv = *reinterpret_cast<const float4*>(qb + (size_t)row * QLD + le);
        Qst[le + 0][row] = qv.x;
        Qst[le + 1][row] = qv.y;
        Qst[le + 2][row] = qv.z;
        Qst[le + 3][row] = qv.w;
    }

    float o[4][4] = {};
    float mrow[4] = {-INFINITY, -INFINITY, -INFINITY, -INFINITY};
    float lrow[4] = {};

    const int NT = CAUSAL ? (blockIdx.x + 1) : (T_SEQ / 64);
    for (int st = 0; st < NT; ++st) {
        int s0 = st << 6;
        const float* kb = qkv + 1024 + (size_t)(b * T_SEQ + s0) * QLD + h * HSZ;
        const float* vb = qkv + 2048 + (size_t)(b * T_SEQ + s0) * QLD + h * HSZ;
#pragma unroll
        for (int r = 0; r < 4; ++r) {
            int row = lr + (r << 4);
            float4 kv = *reinterpret_cast<const float4*>(kb + (size_t)row * QLD + le);
            KPs[le + 0][row] = kv.x;
            KPs[le + 1][row] = kv.y;
            KPs[le + 2][row] = kv.z;
            KPs[le + 3][row] = kv.w;
            float4 vv = *reinterpret_cast<const float4*>(vb + (size_t)row * QLD + le);
            *reinterpret_cast<float4*>(&Vs[row][le]) = vv;
        }
        __syncthreads();

        float s[4][4] = {};
        for (int e = 0; e < 64; ++e) {
            float4 a = *reinterpret_cast<const float4*>(&Qst[e][ty << 2]);
            float4 bb = *reinterpret_cast<const float4*>(&KPs[e][tx << 2]);
            float av[4] = {a.x, a.y, a.z, a.w};
            float bv[4] = {bb.x, bb.y, bb.z, bb.w};
#pragma unroll
            for (int i = 0; i < 4; ++i)
#pragma unroll
                for (int j = 0; j < 4; ++j) s[i][j] += av[i] * bv[j];
        }
#pragma unroll
        for (int i = 0; i < 4; ++i)
#pragma unroll
            for (int j = 0; j < 4; ++j) {
                float v = 8.0f * s[i][j];
                if (CAUSAL) {
                    int scol = s0 + (tx << 2) + j;
                    int trow = t0 + (ty << 2) + i;
                    if (scol > trow) v = -INFINITY;
                }
                s[i][j] = v;
            }

#pragma unroll
        for (int i = 0; i < 4; ++i) {
            float rmax = fmaxf(fmaxf(s[i][0], s[i][1]), fmaxf(s[i][2], s[i][3]));
#pragma unroll
            for (int msk = 1; msk < 16; msk <<= 1)
                rmax = fmaxf(rmax, __shfl_xor(rmax, msk));
            float mn = fmaxf(mrow[i], rmax);
            float fsc = __expf(mrow[i] - mn);
            float rs = 0.f;
#pragma unroll
            for (int j = 0; j < 4; ++j) {
                float pv = __expf(s[i][j] - mn);
                s[i][j] = pv;
                rs += pv;
            }
#pragma unroll
            for (int msk = 1; msk < 16; msk <<= 1) rs += __shfl_xor(rs, msk);
            lrow[i] = lrow[i] * fsc + rs;
            mrow[i] = mn;
#pragma unroll
            for (int j = 0; j < 4; ++j) o[i][j] *= fsc;
        }
        __syncthreads();

#pragma unroll
        for (int i = 0; i < 4; ++i)
#pragma unroll
            for (int j = 0; j < 4; ++j)
                KPs[(tx << 2) + j][(ty << 2) + i] = s[i][j];
        __syncthreads();

        for (int kk = 0; kk < 64; ++kk) {
            float4 a = *reinterpret_cast<const float4*>(&KPs[kk][ty << 2]);
            float4 bb = *reinterpret_cast<const float4*>(&Vs[kk][tx << 2]);
            float av[4] = {a.x, a.y, a.z, a.w};
            float bv[4] = {bb.x, bb.y, bb.z, bb.w};
#pragma unroll
            for (int i = 0; i < 4; ++i)
#pragma unroll
                for (int j = 0; j < 4; ++j) o[i][j] += av[i] * bv[j];
        }
        __syncthreads();
    }

#pragma unroll
    for (int i = 0; i < 4; ++i) {
        float inv = 1.f / lrow[i];
        size_t orow = (size_t)(b * T_SEQ + t0 + (ty << 2) + i) * DMODEL
                      + h * HSZ + (tx << 2);
#pragma unroll
        for (int j = 0; j < 4; ++j) {
            f16 h_, m_;
            split2h(o[i][j] * inv, h_, m_);
            outp[orow + j] = h_;
            outp[planeStride + orow + j] = m_;
        }
    }
}

// ---------------------------------------------------------------------------
extern "C" void kernel_launch(void* const* d_in, const int* in_sizes, int n_in,
                              void* d_out, int out_size, void* d_ws, size_t ws_size,
                              hipStream_t stream) {
    const int*   idx = (const int*)  d_in[0];
    const float* tok = (const float*)d_in[1];
    const float* pos = (const float*)d_in[2];
    const float* Wq  = (const float*)d_in[3];
    const float* bq  = (const float*)d_in[4];
    const float* Wk  = (const float*)d_in[5];
    const float* bk  = (const float*)d_in[6];
    const float* Wv  = (const float*)d_in[7];
    const float* bv  = (const float*)d_in[8];
    const float* Wo  = (const float*)d_in[9];
    const float* bo  = (const float*)d_in[10];
    const float* W1  = (const float*)d_in[11];
    const float* b1  = (const float*)d_in[12];
    const float* W2  = (const float*)d_in[13];
    const float* b2  = (const float*)d_in[14];
    const float* nw  = (const float*)d_in[15];
    const float* fnw = (const float*)d_in[16];
    const float* Wf  = (const float*)d_in[17];
    const float* bf  = (const float*)d_in[18];
    float* out = (float*)d_out;

    const size_t SZ   = (size_t)BT * DMODEL;    // 4M
    const size_t HSZF = (size_t)BT * DFF;       // 16M

    char* w = (char*)d_ws;
    auto alloc = [&](size_t bytes) {
        char* p = w;
        w += (bytes + 255) & ~(size_t)255;
        return p;
    };
    float* x    = (float*)alloc(SZ * 4);
    float* xo   = (float*)alloc(SZ * 4);
    f16*   xnp  = (f16*)  alloc(SZ * 2 * 2);                  // 2 planes
    float* qkv  = (float*)alloc((size_t)BT * QLD * 4);
    f16*   aop  = (f16*)  alloc(SZ * 2 * 2);
    f16*   hbp  = (f16*)  alloc(HSZF * 2 * 2);                // ffn hidden planes
    char*  wreg = alloc(132ull * 1024 * 1024);
    f16*   qkvTp = (f16*)wreg;                                // 2 x 3072x1024
    f16*   woTp  = qkvTp + 2ull * QLD * DMODEL;               // 2 x 1024x1024
    f16*   w1Tp  = woTp  + 2ull * DMODEL * DMODEL;            // 2 x 4096x1024
    f16*   w2Tp  = w1Tp  + 2ull * DFF * DMODEL;               // 2 x 1024x4096
    f16*   wfp   = (f16*)wreg;                                // 2 x 32000x1024
    float* catb  = (float*)alloc((size_t)NLAYER * QLD * 4);

    cat_bias<<<(NLAYER * QLD) / 256, 256, 0, stream>>>(bq, bk, bv, catb);
    embed_kernel<<<BT, 256, 0, stream>>>(idx, tok, pos, x);

    for (int l = 0; l < NLAYER; ++l) {
        const float* nwl = nw + (size_t)l * DMODEL;
        const float* catbl = catb + (size_t)l * QLD;
        const float* bol = bo + (size_t)l * DMODEL;
        const float* b1l = b1 + (size_t)l * DFF;
        const float* b2l = b2 + (size_t)l * DMODEL;

        // split this layer's weights into transposed f16 planes (h, m')
        {
            long izs = (long)DMODEL * HSZ;
            long ozi = (long)HSZ * DMODEL;
            size_t ps = (size_t)QLD * DMODEL;
            dim3 g(HSZ / 32, DMODEL / 32, NHEAD);
            const float* Wql = Wq + (size_t)l * NHEAD * DMODEL * HSZ;
            const float* Wkl = Wk + (size_t)l * NHEAD * DMODEL * HSZ;
            const float* Wvl = Wv + (size_t)l * NHEAD * DMODEL * HSZ;
            transpose_split<<<g, 256, 0, stream>>>(Wql, qkvTp,                 ps, DMODEL, HSZ, izs, ozi);
            transpose_split<<<g, 256, 0, stream>>>(Wkl, qkvTp + 1024ul * 1024, ps, DMODEL, HSZ, izs, ozi);
            transpose_split<<<g, 256, 0, stream>>>(Wvl, qkvTp + 2048ul * 1024, ps, DMODEL, HSZ, izs, ozi);
            transpose_split<<<dim3(DMODEL / 32, DMODEL / 32, 1), 256, 0, stream>>>(
                Wo + (size_t)l * DMODEL * DMODEL, woTp, (size_t)DMODEL * DMODEL, DMODEL, DMODEL, 0, 0);
            transpose_split<<<dim3(DFF / 32, DMODEL / 32, 1), 256, 0, stream>>>(
                W1 + (size_t)l * DMODEL * DFF, w1Tp, (size_t)DFF * DMODEL, DMODEL, DFF, 0, 0);
            transpose_split<<<dim3(DMODEL / 32, DFF / 32, 1), 256, 0, stream>>>(
                W2 + (size_t)l * DMODEL * DFF, w2Tp, (size_t)DMODEL * DFF, DFF, DMODEL, 0, 0);
        }

        auto attn = [&](const float* resid, float* outp, int causal) {
            gemm_f16<false, false><<<dim3((BT / 128) * (QLD / 128)), 512, 0, stream>>>(
                xnp, SZ, qkvTp, (size_t)QLD * DMODEL, catbl, nullptr,
                qkv, nullptr, 0, QLD, DMODEL);
            if (causal)
                attn_fused<1><<<dim3(T_SEQ / 64, BATCH * NHEAD), 256, 0, stream>>>(qkv, aop, SZ);
            else
                attn_fused<0><<<dim3(T_SEQ / 64, BATCH * NHEAD), 256, 0, stream>>>(qkv, aop, SZ);
            gemm_f16<false, false><<<dim3((BT / 128) * (DMODEL / 128)), 512, 0, stream>>>(
                aop, SZ, woTp, (size_t)DMODEL * DMODEL, bol, resid,
                outp, nullptr, 0, DMODEL, DMODEL);
        };

        // x_out1 = x + attn(rms(x), unmasked)
        rms_split<<<BT, 256, 0, stream>>>(x, nwl, xnp, SZ);
        attn(x, xo, 0);
        // x_out2 = x + ffn(rms(x_out1))      (residual from ORIGINAL x)
        rms_split<<<BT, 256, 0, stream>>>(xo, nwl, xnp, SZ);
        gemm_f16<true, true><<<dim3((BT / 128) * (DFF / 128)), 512, 0, stream>>>(
            xnp, SZ, w1Tp, (size_t)DFF * DMODEL, b1l, nullptr,
            nullptr, hbp, HSZF, DFF, DMODEL);
        gemm_f16<false, false><<<dim3((BT / 128) * (DMODEL / 128)), 512, 0, stream>>>(
            hbp, HSZF, w2Tp, (size_t)DMODEL * DFF, b2l, x,
            xo, nullptr, 0, DMODEL, DFF);
        // x = x_out2 + attn(rms(x_out2), masked)
        rms_split<<<BT, 256, 0, stream>>>(xo, nwl, xnp, SZ);
        attn(xo, x, 1);
    }

    // final: logits = rms(x, fnw) @ Wf + bf
    rms_split<<<BT, 256, 0, stream>>>(x, fnw, xnp, SZ);
    transpose_split<<<dim3(VOCAB / 32, DMODEL / 32, 1), 256, 0, stream>>>(
        Wf, wfp, (size_t)VOCAB * DMODEL, DMODEL, VOCAB, 0, 0);
    gemm_f16<false, false><<<dim3((BT / 128) * (VOCAB / 128)), 512, 0, stream>>>(
        xnp, SZ, wfp, (size_t)VOCAB * DMODEL, bf, nullptr,
        out, nullptr, 0, VOCAB, DMODEL);
}

// Round 13
// 7524.329 us; speedup vs baseline: 1.8829x; 1.1552x over previous
//
#include <hip/hip_runtime.h>
#include <hip/hip_bf16.h>
#include <cstdint>
#include <cstddef>

#define T_SEQ   512
#define BATCH   8
#define BT      4096
#define DMODEL  1024
#define NHEAD   16
#define HSZ     64
#define NLAYER  8
#define DFF     4096
#define VOCAB   32000
#define EPS     1e-6f
#define NEG_SLOPE 0.1f
#define QLD     3072    // fused qkv row stride
#define MSCALE  2048.0f
#define MINV    (1.0f / 2048.0f)

typedef _Float16 f16;
typedef __attribute__((ext_vector_type(8))) _Float16 half8;
typedef __attribute__((ext_vector_type(4))) float f32x4;

#define AS1 __attribute__((address_space(1)))
#define AS3 __attribute__((address_space(3)))

// counted-vmcnt wait fused with barrier: the N newest vmem ops stay in flight.
#define WAIT_BAR(N) asm volatile("s_waitcnt vmcnt(" #N ")\ns_barrier" ::: "memory")
#define LGKM_BAR()  asm volatile("s_waitcnt lgkmcnt(0)\ns_barrier" ::: "memory")

// ---------------------------------------------------------------------------
__global__ void embed_kernel(const int* __restrict__ idx,
                             const float* __restrict__ tok,
                             const float* __restrict__ pos,
                             float* __restrict__ x) {
    int bt  = blockIdx.x;
    int tid = threadIdx.x;
    int token = idx[bt];
    int t = bt & (T_SEQ - 1);
    float4 a = reinterpret_cast<const float4*>(tok + (size_t)token * DMODEL)[tid];
    float4 p = reinterpret_cast<const float4*>(pos + (size_t)t * DMODEL)[tid];
    reinterpret_cast<float4*>(x + (size_t)bt * DMODEL)[tid] =
        make_float4(a.x + p.x, a.y + p.y, a.z + p.z, a.w + p.w);
}

// ---------------------------------------------------------------------------
// f16 2-plane split with scaled low plane: x ~= h + m/2048, residual ~2^-23|x|.
__device__ __forceinline__ void split2h(float v, f16& h, f16& m) {
    f16 hh = (f16)v;
    float hf = (float)hh;
    if (fabsf(hf) < 6.103515625e-05f) { hh = (f16)0.0f; hf = 0.0f; }
    h = hh;
    m = (f16)((v - hf) * MSCALE);
}

// ---------------------------------------------------------------------------
// rmsnorm f32 -> 2 f16 planes (h, m')
__global__ void rms_split(const float* __restrict__ x,
                          const float* __restrict__ w,
                          f16* __restrict__ out, size_t planeStride) {
    int row = blockIdx.x;
    int tid = threadIdx.x;
    float4 v = reinterpret_cast<const float4*>(x + (size_t)row * DMODEL)[tid];
    float ss = v.x * v.x + v.y * v.y + v.z * v.z + v.w * v.w;
#pragma unroll
    for (int off = 32; off > 0; off >>= 1) ss += __shfl_xor(ss, off);
    __shared__ float wsum[4];
    if ((tid & 63) == 0) wsum[tid >> 6] = ss;
    __syncthreads();
    float tot = wsum[0] + wsum[1] + wsum[2] + wsum[3];
    float scale = rsqrtf(tot * (1.0f / DMODEL) + EPS);
    float4 wv = reinterpret_cast<const float4*>(w)[tid];
    float o[4] = {v.x * scale * wv.x, v.y * scale * wv.y,
                  v.z * scale * wv.z, v.w * scale * wv.w};
    size_t base = (size_t)row * DMODEL + tid * 4;
#pragma unroll
    for (int j = 0; j < 4; ++j) {
        f16 h, m;
        split2h(o[j], h, m);
        out[base + j] = h;
        out[planeStride + base + j] = m;
    }
}

// ---------------------------------------------------------------------------
// Tiled transpose + split: in (R,C) f32 -> out (C,R) f16 x 2 planes
__global__ __launch_bounds__(256)
void transpose_split(const float* __restrict__ in, f16* __restrict__ out,
                     size_t planeStride, int R, int C,
                     long izs, long ozi) {
    int z = blockIdx.z;
    in  += (size_t)z * izs;
    out += (size_t)z * ozi;
    __shared__ float tile[32][33];
    int r0 = blockIdx.y << 5, c0 = blockIdx.x << 5;
    int tx = threadIdx.x & 31, ty = threadIdx.x >> 5;
#pragma unroll
    for (int i = 0; i < 4; ++i) {
        int r = ty + (i << 3);
        tile[r][tx] = in[(size_t)(r0 + r) * C + c0 + tx];
    }
    __syncthreads();
#pragma unroll
    for (int i = 0; i < 4; ++i) {
        int c = ty + (i << 3);
        float v = tile[tx][c];
        size_t o = (size_t)(c0 + c) * R + r0 + tx;
        f16 h, m;
        split2h(v, h, m);
        out[o] = h;
        out[planeStride + o] = m;
    }
}

// concat per-layer qkv bias into (L, 3072) f32
__global__ void cat_bias(const float* __restrict__ bq, const float* __restrict__ bk,
                         const float* __restrict__ bv, float* __restrict__ cb) {
    int i = blockIdx.x * 256 + threadIdx.x;
    int l = i / QLD, r = i - l * QLD;
    const float* src = (r < 1024) ? bq : ((r < 2048) ? bk : bv);
    cb[i] = src[l * 1024 + (r & 1023)];
}

// ---------------------------------------------------------------------------
// f16 split-GEMM, 3 passes, 2 accumulators, B-single-buffer.
// r12's register-liveness layout (B frags before mid-barrier, A frags per-i
// after it) + the MISSING end-of-body LGKM_BAR: without it, a fast wave's
// next-top STAGE_A could overwrite As[cur] while a slow wave still reads it
// (r12's failure). The end barrier proves all waves' ds_reads are complete
// before any wave issues the next staging. vmcnt FIFO: at top of step t,
// outstanding = A(t):2 + B(t):2; issue A(t+1):2; WAIT_BAR(2) drains A(t),B(t).
template <bool LRELU, bool SPLITOUT>
__global__ __launch_bounds__(512, 4)
void gemm_f16(const f16* __restrict__ A, size_t aPS,
              const f16* __restrict__ Bt, size_t bPS,
              const float* __restrict__ bias,
              const float* __restrict__ resid,
              float* __restrict__ C, f16* __restrict__ Cp, size_t cPS,
              int N, int K) {
    __shared__ f16 As[2][2 * 4096];   // 128 rows x 32 k per plane, dbuf
    __shared__ f16 Bs[2 * 4096];      // single buffer

    int chunk = gridDim.x >> 3;
    int bid = blockIdx.x;
    int sw = (bid & 7) * chunk + (bid >> 3);
    int m0 = (sw & 31) << 7;
    int n0 = (sw >> 5) << 7;

    const int tid  = threadIdx.x;
    const int lane = tid & 63;
    const int wid  = tid >> 6;

    const int ssk = (((tid & 3) ^ ((tid >> 3) & 3)) << 3);
    const size_t offA = (size_t)(m0 + (tid >> 2)) * K + ssk;
    const size_t offB = (size_t)(n0 + (tid >> 2)) * K + ssk;
    const int ldst = wid * 512;          // wave-uniform LDS elem base

    f32x4 accH[4][2], accM[4][2];
#pragma unroll
    for (int i = 0; i < 4; ++i)
#pragma unroll
        for (int j = 0; j < 2; ++j) {
            accH[i][j] = (f32x4){0.f, 0.f, 0.f, 0.f};
            accM[i][j] = (f32x4){0.f, 0.f, 0.f, 0.f};
        }

    const int wr = wid >> 2, wc = wid & 3;
    const int fm = lane & 15;
    const int rslot = (((lane >> 4) ^ ((lane >> 1) & 3)) & 3) << 3;
    const int foffA0 = (wr * 64 + fm) * 32 + rslot;          // +i*512 per frag
    const int foffB0 = (wc * 32 + fm) * 32 + rslot;          // +j*512 per frag

    auto STAGE_A = [&](int buf, int k0) {
#pragma unroll
        for (int pp = 0; pp < 2; ++pp)
            __builtin_amdgcn_global_load_lds(
                (const AS1 void*)(A + pp * aPS + offA + k0),
                (AS3 void*)(&As[buf][pp * 4096 + ldst]), 16, 0, 0);
    };
    auto STAGE_B = [&](int k0) {
#pragma unroll
        for (int pp = 0; pp < 2; ++pp)
            __builtin_amdgcn_global_load_lds(
                (const AS1 void*)(Bt + pp * bPS + offB + k0),
                (AS3 void*)(&Bs[pp * 4096 + ldst]), 16, 0, 0);
    };

    const int nt = K >> 5;
    STAGE_A(0, 0);
    STAGE_B(0);
    int cur = 0;
    for (int t = 0; t < nt; ++t) {
        if (t + 1 < nt) {
            STAGE_A(cur ^ 1, (t + 1) << 5);
            WAIT_BAR(2);
        } else {
            WAIT_BAR(0);
        }

        // B fragments only (Bs dies at the barrier below)
        half8 bh[2], bm[2];
#pragma unroll
        for (int j = 0; j < 2; ++j) {
            bh[j] = *(const half8*)(&Bs[foffB0 + j * 512]);
            bm[j] = *(const half8*)(&Bs[4096 + foffB0 + j * 512]);
        }
        LGKM_BAR();                         // all waves' B reads done
        if (t + 1 < nt) STAGE_B((t + 1) << 5);   // overwrite Bs under MFMA

        // per-i: A frags + their MFMAs (short liveness)
#pragma unroll
        for (int i = 0; i < 4; ++i) {
            half8 ah = *(const half8*)(&As[cur][foffA0 + i * 512]);
            half8 am = *(const half8*)(&As[cur][4096 + foffA0 + i * 512]);
#pragma unroll
            for (int j = 0; j < 2; ++j) {
                accM[i][j] = __builtin_amdgcn_mfma_f32_16x16x32_f16(
                    am, bh[j], accM[i][j], 0, 0, 0);
                accM[i][j] = __builtin_amdgcn_mfma_f32_16x16x32_f16(
                    ah, bm[j], accM[i][j], 0, 0, 0);
                accH[i][j] = __builtin_amdgcn_mfma_f32_16x16x32_f16(
                    ah, bh[j], accH[i][j], 0, 0, 0);
            }
        }
        // END-OF-BODY barrier (the r12 fix): all waves' A ds_reads complete
        // before any wave's next-top STAGE_A overwrites As[cur].
        LGKM_BAR();
        cur ^= 1;
    }

    // epilogue: C/D layout col = lane&15, row = (lane>>4)*4 + rr
#pragma unroll
    for (int i = 0; i < 4; ++i) {
        int mbase = m0 + wr * 64 + i * 16 + ((lane >> 4) << 2);
#pragma unroll
        for (int j = 0; j < 2; ++j) {
            int n = n0 + wc * 32 + j * 16 + fm;
            float bv = bias[n];
#pragma unroll
            for (int rr = 0; rr < 4; ++rr) {
                int m = mbase + rr;
                float v = accH[i][j][rr] + accM[i][j][rr] * MINV + bv;
                if (LRELU) v = (v >= 0.f) ? v : NEG_SLOPE * v;
                size_t o = (size_t)m * N + n;
                if (SPLITOUT) {
                    f16 h, mm;
                    split2h(v, h, mm);
                    Cp[o] = h;
                    Cp[cPS + o] = mm;
                } else {
                    if (resid) v += resid[o];
                    C[o] = v;
                }
            }
        }
    }
}

// ---------------------------------------------------------------------------
// Single-pass plain-f16 GEMM for the vocab projection (post-chaos: error
// ~<=0.013 worst-case << 0.0737 threshold). h-planes only, 24KB LDS.
// Same end-of-body barrier fix as gemm_f16.
__global__ __launch_bounds__(512, 4)
void gemm_f16_1p(const f16* __restrict__ A,
                 const f16* __restrict__ Bt,
                 const float* __restrict__ bias,
                 float* __restrict__ C, int N, int K) {
    __shared__ f16 As[2][4096];
    __shared__ f16 Bs[4096];

    int chunk = gridDim.x >> 3;
    int bid = blockIdx.x;
    int sw = (bid & 7) * chunk + (bid >> 3);
    int m0 = (sw & 31) << 7;
    int n0 = (sw >> 5) << 7;

    const int tid  = threadIdx.x;
    const int lane = tid & 63;
    const int wid  = tid >> 6;

    const int ssk = (((tid & 3) ^ ((tid >> 3) & 3)) << 3);
    const size_t offA = (size_t)(m0 + (tid >> 2)) * K + ssk;
    const size_t offB = (size_t)(n0 + (tid >> 2)) * K + ssk;
    const int ldst = wid * 512;

    f32x4 acc[4][2];
#pragma unroll
    for (int i = 0; i < 4; ++i)
#pragma unroll
        for (int j = 0; j < 2; ++j) acc[i][j] = (f32x4){0.f, 0.f, 0.f, 0.f};

    const int wr = wid >> 2, wc = wid & 3;
    const int fm = lane & 15;
    const int rslot = (((lane >> 4) ^ ((lane >> 1) & 3)) & 3) << 3;
    const int foffA0 = (wr * 64 + fm) * 32 + rslot;
    const int foffB0 = (wc * 32 + fm) * 32 + rslot;

    const int nt = K >> 5;
    __builtin_amdgcn_global_load_lds((const AS1 void*)(A + offA),
                                     (AS3 void*)(&As[0][ldst]), 16, 0, 0);
    __builtin_amdgcn_global_load_lds((const AS1 void*)(Bt + offB),
                                     (AS3 void*)(&Bs[ldst]), 16, 0, 0);
    int cur = 0;
    for (int t = 0; t < nt; ++t) {
        if (t + 1 < nt) {
            __builtin_amdgcn_global_load_lds(
                (const AS1 void*)(A + offA + ((t + 1) << 5)),
                (AS3 void*)(&As[cur ^ 1][ldst]), 16, 0, 0);
            WAIT_BAR(1);
        } else {
            WAIT_BAR(0);
        }

        half8 bh[2];
#pragma unroll
        for (int j = 0; j < 2; ++j)
            bh[j] = *(const half8*)(&Bs[foffB0 + j * 512]);
        LGKM_BAR();
        if (t + 1 < nt)
            __builtin_amdgcn_global_load_lds(
                (const AS1 void*)(Bt + offB + ((t + 1) << 5)),
                (AS3 void*)(&Bs[ldst]), 16, 0, 0);

#pragma unroll
        for (int i = 0; i < 4; ++i) {
            half8 ah = *(const half8*)(&As[cur][foffA0 + i * 512]);
#pragma unroll
            for (int j = 0; j < 2; ++j)
                acc[i][j] = __builtin_amdgcn_mfma_f32_16x16x32_f16(
                    ah, bh[j], acc[i][j], 0, 0, 0);
        }
        // END-OF-BODY barrier: A reads complete before next-top STAGE_A.
        LGKM_BAR();
        cur ^= 1;
    }

#pragma unroll
    for (int i = 0; i < 4; ++i) {
        int mbase = m0 + wr * 64 + i * 16 + ((lane >> 4) << 2);
#pragma unroll
        for (int j = 0; j < 2; ++j) {
            int n = n0 + wc * 32 + j * 16 + fm;
            float bv = bias[n];
#pragma unroll
            for (int rr = 0; rr < 4; ++rr) {
                int m = mbase + rr;
                C[(size_t)m * N + n] = acc[i][j][rr] + bv;
            }
        }
    }
}

// ---------------------------------------------------------------------------
// Fused attention (f32 vector, 256 thr): per block one 64-row q-tile of one
// (b,h). Proven structure; epilogue writes 2 f16 planes.
template <int CAUSAL>
__global__ __launch_bounds__(256)
void attn_fused(const float* __restrict__ qkv, f16* __restrict__ outp,
                size_t planeStride) {
    int bh = blockIdx.y;
    int b = bh >> 4, h = bh & 15;
    int t0 = blockIdx.x << 6;
    __shared__ float Qst[64][68];
    __shared__ float KPs[64][68];
    __shared__ float Vs[64][68];
    const int tid = threadIdx.x;
    const int tx = tid & 15, ty = tid >> 4;
    const int lr = tid >> 4, le = (tid & 15) << 2;

    const float* qb = qkv + (size_t)(b * T_SEQ + t0) * QLD + h * HSZ;
#pragma unroll
    for (int r = 0; r < 4; ++r) {
        int row = lr + (r << 4);
        float4 qv = *reinterpret_cast<const float4*>(qb + (size_t)row * QLD + le);
        Qst[le + 0][row] = qv.x;
        Qst[le + 1][row] = qv.y;
        Qst[le + 2][row] = qv.z;
        Qst[le + 3][row] = qv.w;
    }

    float o[4][4] = {};
    float mrow[4] = {-INFINITY, -INFINITY, -INFINITY, -INFINITY};
    float lrow[4] = {};

    const int NT = CAUSAL ? (blockIdx.x + 1) : (T_SEQ / 64);
    for (int st = 0; st < NT; ++st) {
        int s0 = st << 6;
        const float* kb = qkv + 1024 + (size_t)(b * T_SEQ + s0) * QLD + h * HSZ;
        const float* vb = qkv + 2048 + (size_t)(b * T_SEQ + s0) * QLD + h * HSZ;
#pragma unroll
        for (int r = 0; r < 4; ++r) {
            int row = lr + (r << 4);
            float4 kv = *reinterpret_cast<const float4*>(kb + (size_t)row * QLD + le);
            KPs[le + 0][row] = kv.x;
            KPs[le + 1][row] = kv.y;
            KPs[le + 2][row] = kv.z;
            KPs[le + 3][row] = kv.w;
            float4 vv = *reinterpret_cast<const float4*>(vb + (size_t)row * QLD + le);
            *reinterpret_cast<float4*>(&Vs[row][le]) = vv;
        }
        __syncthreads();

        float s[4][4] = {};
        for (int e = 0; e < 64; ++e) {
            float4 a = *reinterpret_cast<const float4*>(&Qst[e][ty << 2]);
            float4 bb = *reinterpret_cast<const float4*>(&KPs[e][tx << 2]);
            float av[4] = {a.x, a.y, a.z, a.w};
            float bv[4] = {bb.x, bb.y, bb.z, bb.w};
#pragma unroll
            for (int i = 0; i < 4; ++i)
#pragma unroll
                for (int j = 0; j < 4; ++j) s[i][j] += av[i] * bv[j];
        }
#pragma unroll
        for (int i = 0; i < 4; ++i)
#pragma unroll
            for (int j = 0; j < 4; ++j) {
                float v = 8.0f * s[i][j];
                if (CAUSAL) {
                    int scol = s0 + (tx << 2) + j;
                    int trow = t0 + (ty << 2) + i;
                    if (scol > trow) v = -INFINITY;
                }
                s[i][j] = v;
            }

#pragma unroll
        for (int i = 0; i < 4; ++i) {
            float rmax = fmaxf(fmaxf(s[i][0], s[i][1]), fmaxf(s[i][2], s[i][3]));
#pragma unroll
            for (int msk = 1; msk < 16; msk <<= 1)
                rmax = fmaxf(rmax, __shfl_xor(rmax, msk));
            float mn = fmaxf(mrow[i], rmax);
            float fsc = __expf(mrow[i] - mn);
            float rs = 0.f;
#pragma unroll
            for (int j = 0; j < 4; ++j) {
                float pv = __expf(s[i][j] - mn);
                s[i][j] = pv;
                rs += pv;
            }
#pragma unroll
            for (int msk = 1; msk < 16; msk <<= 1) rs += __shfl_xor(rs, msk);
            lrow[i] = lrow[i] * fsc + rs;
            mrow[i] = mn;
#pragma unroll
            for (int j = 0; j < 4; ++j) o[i][j] *= fsc;
        }
        __syncthreads();

#pragma unroll
        for (int i = 0; i < 4; ++i)
#pragma unroll
            for (int j = 0; j < 4; ++j)
                KPs[(tx << 2) + j][(ty << 2) + i] = s[i][j];
        __syncthreads();

        for (int kk = 0; kk < 64; ++kk) {
            float4 a = *reinterpret_cast<const float4*>(&KPs[kk][ty << 2]);
            float4 bb = *reinterpret_cast<const float4*>(&Vs[kk][tx << 2]);
            float av[4] = {a.x, a.y, a.z, a.w};
            float bv[4] = {bb.x, bb.y, bb.z, bb.w};
#pragma unroll
            for (int i = 0; i < 4; ++i)
#pragma unroll
                for (int j = 0; j < 4; ++j) o[i][j] += av[i] * bv[j];
        }
        __syncthreads();
    }

#pragma unroll
    for (int i = 0; i < 4; ++i) {
        float inv = 1.f / lrow[i];
        size_t orow = (size_t)(b * T_SEQ + t0 + (ty << 2) + i) * DMODEL
                      + h * HSZ + (tx << 2);
#pragma unroll
        for (int j = 0; j < 4; ++j) {
            f16 h_, m_;
            split2h(o[i][j] * inv, h_, m_);
            outp[orow + j] = h_;
            outp[planeStride + orow + j] = m_;
        }
    }
}

// ---------------------------------------------------------------------------
extern "C" void kernel_launch(void* const* d_in, const int* in_sizes, int n_in,
                              void* d_out, int out_size, void* d_ws, size_t ws_size,
                              hipStream_t stream) {
    const int*   idx = (const int*)  d_in[0];
    const float* tok = (const float*)d_in[1];
    const float* pos = (const float*)d_in[2];
    const float* Wq  = (const float*)d_in[3];
    const float* bq  = (const float*)d_in[4];
    const float* Wk  = (const float*)d_in[5];
    const float* bk  = (const float*)d_in[6];
    const float* Wv  = (const float*)d_in[7];
    const float* bv  = (const float*)d_in[8];
    const float* Wo  = (const float*)d_in[9];
    const float* bo  = (const float*)d_in[10];
    const float* W1  = (const float*)d_in[11];
    const float* b1  = (const float*)d_in[12];
    const float* W2  = (const float*)d_in[13];
    const float* b2  = (const float*)d_in[14];
    const float* nw  = (const float*)d_in[15];
    const float* fnw = (const float*)d_in[16];
    const float* Wf  = (const float*)d_in[17];
    const float* bf  = (const float*)d_in[18];
    float* out = (float*)d_out;

    const size_t SZ   = (size_t)BT * DMODEL;    // 4M
    const size_t HSZF = (size_t)BT * DFF;       // 16M

    char* w = (char*)d_ws;
    auto alloc = [&](size_t bytes) {
        char* p = w;
        w += (bytes + 255) & ~(size_t)255;
        return p;
    };
    float* x    = (float*)alloc(SZ * 4);
    float* xo   = (float*)alloc(SZ * 4);
    f16*   xnp  = (f16*)  alloc(SZ * 2 * 2);                  // 2 planes
    float* qkv  = (float*)alloc((size_t)BT * QLD * 4);
    f16*   aop  = (f16*)  alloc(SZ * 2 * 2);
    f16*   hbp  = (f16*)  alloc(HSZF * 2 * 2);                // ffn hidden planes
    char*  wreg = alloc(132ull * 1024 * 1024);
    f16*   qkvTp = (f16*)wreg;                                // 2 x 3072x1024
    f16*   woTp  = qkvTp + 2ull * QLD * DMODEL;               // 2 x 1024x1024
    f16*   w1Tp  = woTp  + 2ull * DMODEL * DMODEL;            // 2 x 4096x1024
    f16*   w2Tp  = w1Tp  + 2ull * DFF * DMODEL;               // 2 x 1024x4096
    f16*   wfp   = (f16*)wreg;                                // 1 x 32000x1024 (h only)
    float* catb  = (float*)alloc((size_t)NLAYER * QLD * 4);

    cat_bias<<<(NLAYER * QLD) / 256, 256, 0, stream>>>(bq, bk, bv, catb);
    embed_kernel<<<BT, 256, 0, stream>>>(idx, tok, pos, x);

    for (int l = 0; l < NLAYER; ++l) {
        const float* nwl = nw + (size_t)l * DMODEL;
        const float* catbl = catb + (size_t)l * QLD;
        const float* bol = bo + (size_t)l * DMODEL;
        const float* b1l = b1 + (size_t)l * DFF;
        const float* b2l = b2 + (size_t)l * DMODEL;

        // split this layer's weights into transposed f16 planes (h, m')
        {
            long izs = (long)DMODEL * HSZ;
            long ozi = (long)HSZ * DMODEL;
            size_t ps = (size_t)QLD * DMODEL;
            dim3 g(HSZ / 32, DMODEL / 32, NHEAD);
            const float* Wql = Wq + (size_t)l * NHEAD * DMODEL * HSZ;
            const float* Wkl = Wk + (size_t)l * NHEAD * DMODEL * HSZ;
            const float* Wvl = Wv + (size_t)l * NHEAD * DMODEL * HSZ;
            transpose_split<<<g, 256, 0, stream>>>(Wql, qkvTp,                 ps, DMODEL, HSZ, izs, ozi);
            transpose_split<<<g, 256, 0, stream>>>(Wkl, qkvTp + 1024ul * 1024, ps, DMODEL, HSZ, izs, ozi);
            transpose_split<<<g, 256, 0, stream>>>(Wvl, qkvTp + 2048ul * 1024, ps, DMODEL, HSZ, izs, ozi);
            transpose_split<<<dim3(DMODEL / 32, DMODEL / 32, 1), 256, 0, stream>>>(
                Wo + (size_t)l * DMODEL * DMODEL, woTp, (size_t)DMODEL * DMODEL, DMODEL, DMODEL, 0, 0);
            transpose_split<<<dim3(DFF / 32, DMODEL / 32, 1), 256, 0, stream>>>(
                W1 + (size_t)l * DMODEL * DFF, w1Tp, (size_t)DFF * DMODEL, DMODEL, DFF, 0, 0);
            transpose_split<<<dim3(DMODEL / 32, DFF / 32, 1), 256, 0, stream>>>(
                W2 + (size_t)l * DMODEL * DFF, w2Tp, (size_t)DMODEL * DFF, DFF, DMODEL, 0, 0);
        }

        auto attn = [&](const float* resid, float* outp, int causal) {
            gemm_f16<false, false><<<dim3((BT / 128) * (QLD / 128)), 512, 0, stream>>>(
                xnp, SZ, qkvTp, (size_t)QLD * DMODEL, catbl, nullptr,
                qkv, nullptr, 0, QLD, DMODEL);
            if (causal)
                attn_fused<1><<<dim3(T_SEQ / 64, BATCH * NHEAD), 256, 0, stream>>>(qkv, aop, SZ);
            else
                attn_fused<0><<<dim3(T_SEQ / 64, BATCH * NHEAD), 256, 0, stream>>>(qkv, aop, SZ);
            gemm_f16<false, false><<<dim3((BT / 128) * (DMODEL / 128)), 512, 0, stream>>>(
                aop, SZ, woTp, (size_t)DMODEL * DMODEL, bol, resid,
                outp, nullptr, 0, DMODEL, DMODEL);
        };

        // x_out1 = x + attn(rms(x), unmasked)
        rms_split<<<BT, 256, 0, stream>>>(x, nwl, xnp, SZ);
        attn(x, xo, 0);
        // x_out2 = x + ffn(rms(x_out1))      (residual from ORIGINAL x)
        rms_split<<<BT, 256, 0, stream>>>(xo, nwl, xnp, SZ);
        gemm_f16<true, true><<<dim3((BT / 128) * (DFF / 128)), 512, 0, stream>>>(
            xnp, SZ, w1Tp, (size_t)DFF * DMODEL, b1l, nullptr,
            nullptr, hbp, HSZF, DFF, DMODEL);
        gemm_f16<false, false><<<dim3((BT / 128) * (DMODEL / 128)), 512, 0, stream>>>(
            hbp, HSZF, w2Tp, (size_t)DMODEL * DFF, b2l, x,
            xo, nullptr, 0, DMODEL, DFF);
        // x = x_out2 + attn(rms(x_out2), masked)
        rms_split<<<BT, 256, 0, stream>>>(xo, nwl, xnp, SZ);
        attn(xo, x, 1);
    }

    // final: logits = rms(x, fnw) @ Wf + bf   (single-pass f16)
    rms_split<<<BT, 256, 0, stream>>>(x, fnw, xnp, SZ);
    transpose_split<<<dim3(VOCAB / 32, DMODEL / 32, 1), 256, 0, stream>>>(
        Wf, wfp, (size_t)VOCAB * DMODEL, DMODEL, VOCAB, 0, 0);
    gemm_f16_1p<<<dim3((BT / 128) * (VOCAB / 128)), 512, 0, stream>>>(
        xnp, wfp, bf, out, VOCAB, DMODEL);
}

// Round 14
// 6153.920 us; speedup vs baseline: 2.3022x; 1.2227x over previous
//
#include <hip/hip_runtime.h>
#include <hip/hip_bf16.h>
#include <cstdint>
#include <cstddef>

#define T_SEQ   512
#define BATCH   8
#define BT      4096
#define DMODEL  1024
#define NHEAD   16
#define HSZ     64
#define NLAYER  8
#define DFF     4096
#define VOCAB   32000
#define EPS     1e-6f
#define NEG_SLOPE 0.1f
#define QLD     3072
#define MSCALE  2048.0f
#define MINV    (1.0f / 2048.0f)

typedef _Float16 f16;
typedef __attribute__((ext_vector_type(8))) _Float16 half8;
typedef __attribute__((ext_vector_type(4))) _Float16 half4;
typedef __attribute__((ext_vector_type(4))) float f32x4;

#define AS1 __attribute__((address_space(1)))
#define AS3 __attribute__((address_space(3)))

#define WAIT_BAR(N) asm volatile("s_waitcnt vmcnt(" #N ")\ns_barrier" ::: "memory")
#define LGKM_BAR()  asm volatile("s_waitcnt lgkmcnt(0)\ns_barrier" ::: "memory")

// ---------------------------------------------------------------------------
__global__ void embed_kernel(const int* __restrict__ idx,
                             const float* __restrict__ tok,
                             const float* __restrict__ pos,
                             float* __restrict__ x) {
    int bt  = blockIdx.x;
    int tid = threadIdx.x;
    int token = idx[bt];
    int t = bt & (T_SEQ - 1);
    float4 a = reinterpret_cast<const float4*>(tok + (size_t)token * DMODEL)[tid];
    float4 p = reinterpret_cast<const float4*>(pos + (size_t)t * DMODEL)[tid];
    reinterpret_cast<float4*>(x + (size_t)bt * DMODEL)[tid] =
        make_float4(a.x + p.x, a.y + p.y, a.z + p.z, a.w + p.w);
}

// ---------------------------------------------------------------------------
__device__ __forceinline__ void split2h(float v, f16& h, f16& m) {
    f16 hh = (f16)v;
    float hf = (float)hh;
    if (fabsf(hf) < 6.103515625e-05f) { hh = (f16)0.0f; hf = 0.0f; }
    h = hh;
    m = (f16)((v - hf) * MSCALE);
}

// ---------------------------------------------------------------------------
__global__ void rms_split(const float* __restrict__ x,
                          const float* __restrict__ w,
                          f16* __restrict__ out, size_t planeStride) {
    int row = blockIdx.x;
    int tid = threadIdx.x;
    float4 v = reinterpret_cast<const float4*>(x + (size_t)row * DMODEL)[tid];
    float ss = v.x * v.x + v.y * v.y + v.z * v.z + v.w * v.w;
#pragma unroll
    for (int off = 32; off > 0; off >>= 1) ss += __shfl_xor(ss, off);
    __shared__ float wsum[4];
    if ((tid & 63) == 0) wsum[tid >> 6] = ss;
    __syncthreads();
    float tot = wsum[0] + wsum[1] + wsum[2] + wsum[3];
    float scale = rsqrtf(tot * (1.0f / DMODEL) + EPS);
    float4 wv = reinterpret_cast<const float4*>(w)[tid];
    float o[4] = {v.x * scale * wv.x, v.y * scale * wv.y,
                  v.z * scale * wv.z, v.w * scale * wv.w};
    size_t base = (size_t)row * DMODEL + tid * 4;
#pragma unroll
    for (int j = 0; j < 4; ++j) {
        f16 h, m;
        split2h(o[j], h, m);
        out[base + j] = h;
        out[planeStride + base + j] = m;
    }
}

// ---------------------------------------------------------------------------
__global__ __launch_bounds__(256)
void transpose_split(const float* __restrict__ in, f16* __restrict__ out,
                     size_t planeStride, int R, int C,
                     long izs, long ozi) {
    int z = blockIdx.z;
    in  += (size_t)z * izs;
    out += (size_t)z * ozi;
    __shared__ float tile[32][33];
    int r0 = blockIdx.y << 5, c0 = blockIdx.x << 5;
    int tx = threadIdx.x & 31, ty = threadIdx.x >> 5;
#pragma unroll
    for (int i = 0; i < 4; ++i) {
        int r = ty + (i << 3);
        tile[r][tx] = in[(size_t)(r0 + r) * C + c0 + tx];
    }
    __syncthreads();
#pragma unroll
    for (int i = 0; i < 4; ++i) {
        int c = ty + (i << 3);
        float v = tile[tx][c];
        size_t o = (size_t)(c0 + c) * R + r0 + tx;
        f16 h, m;
        split2h(v, h, m);
        out[o] = h;
        out[planeStride + o] = m;
    }
}

// concat per-layer qkv bias into (L, 3072) f32
__global__ void cat_bias(const float* __restrict__ bq, const float* __restrict__ bk,
                         const float* __restrict__ bv, float* __restrict__ cb) {
    int i = blockIdx.x * 256 + threadIdx.x;
    int l = i / QLD, r = i - l * QLD;
    const float* src = (r < 1024) ? bq : ((r < 2048) ? bk : bv);
    cb[i] = src[l * 1024 + (r & 1023)];
}

// ---------------------------------------------------------------------------
// f16 split-GEMM (r13-identical, canary-validated): 3 passes, 2 accumulators,
// B-single-buffer, end-of-body LGKM_BAR.
template <bool LRELU, bool SPLITOUT>
__global__ __launch_bounds__(512, 4)
void gemm_f16(const f16* __restrict__ A, size_t aPS,
              const f16* __restrict__ Bt, size_t bPS,
              const float* __restrict__ bias,
              const float* __restrict__ resid,
              float* __restrict__ C, f16* __restrict__ Cp, size_t cPS,
              int N, int K) {
    __shared__ f16 As[2][2 * 4096];
    __shared__ f16 Bs[2 * 4096];

    int chunk = gridDim.x >> 3;
    int bid = blockIdx.x;
    int sw = (bid & 7) * chunk + (bid >> 3);
    int m0 = (sw & 31) << 7;
    int n0 = (sw >> 5) << 7;

    const int tid  = threadIdx.x;
    const int lane = tid & 63;
    const int wid  = tid >> 6;

    const int ssk = (((tid & 3) ^ ((tid >> 3) & 3)) << 3);
    const size_t offA = (size_t)(m0 + (tid >> 2)) * K + ssk;
    const size_t offB = (size_t)(n0 + (tid >> 2)) * K + ssk;
    const int ldst = wid * 512;

    f32x4 accH[4][2], accM[4][2];
#pragma unroll
    for (int i = 0; i < 4; ++i)
#pragma unroll
        for (int j = 0; j < 2; ++j) {
            accH[i][j] = (f32x4){0.f, 0.f, 0.f, 0.f};
            accM[i][j] = (f32x4){0.f, 0.f, 0.f, 0.f};
        }

    const int wr = wid >> 2, wc = wid & 3;
    const int fm = lane & 15;
    const int rslot = (((lane >> 4) ^ ((lane >> 1) & 3)) & 3) << 3;
    const int foffA0 = (wr * 64 + fm) * 32 + rslot;
    const int foffB0 = (wc * 32 + fm) * 32 + rslot;

    auto STAGE_A = [&](int buf, int k0) {
#pragma unroll
        for (int pp = 0; pp < 2; ++pp)
            __builtin_amdgcn_global_load_lds(
                (const AS1 void*)(A + pp * aPS + offA + k0),
                (AS3 void*)(&As[buf][pp * 4096 + ldst]), 16, 0, 0);
    };
    auto STAGE_B = [&](int k0) {
#pragma unroll
        for (int pp = 0; pp < 2; ++pp)
            __builtin_amdgcn_global_load_lds(
                (const AS1 void*)(Bt + pp * bPS + offB + k0),
                (AS3 void*)(&Bs[pp * 4096 + ldst]), 16, 0, 0);
    };

    const int nt = K >> 5;
    STAGE_A(0, 0);
    STAGE_B(0);
    int cur = 0;
    for (int t = 0; t < nt; ++t) {
        if (t + 1 < nt) {
            STAGE_A(cur ^ 1, (t + 1) << 5);
            WAIT_BAR(2);
        } else {
            WAIT_BAR(0);
        }

        half8 bh[2], bm[2];
#pragma unroll
        for (int j = 0; j < 2; ++j) {
            bh[j] = *(const half8*)(&Bs[foffB0 + j * 512]);
            bm[j] = *(const half8*)(&Bs[4096 + foffB0 + j * 512]);
        }
        LGKM_BAR();
        if (t + 1 < nt) STAGE_B((t + 1) << 5);

#pragma unroll
        for (int i = 0; i < 4; ++i) {
            half8 ah = *(const half8*)(&As[cur][foffA0 + i * 512]);
            half8 am = *(const half8*)(&As[cur][4096 + foffA0 + i * 512]);
#pragma unroll
            for (int j = 0; j < 2; ++j) {
                accM[i][j] = __builtin_amdgcn_mfma_f32_16x16x32_f16(
                    am, bh[j], accM[i][j], 0, 0, 0);
                accM[i][j] = __builtin_amdgcn_mfma_f32_16x16x32_f16(
                    ah, bm[j], accM[i][j], 0, 0, 0);
                accH[i][j] = __builtin_amdgcn_mfma_f32_16x16x32_f16(
                    ah, bh[j], accH[i][j], 0, 0, 0);
            }
        }
        LGKM_BAR();
        cur ^= 1;
    }

#pragma unroll
    for (int i = 0; i < 4; ++i) {
        int mbase = m0 + wr * 64 + i * 16 + ((lane >> 4) << 2);
#pragma unroll
        for (int j = 0; j < 2; ++j) {
            int n = n0 + wc * 32 + j * 16 + fm;
            float bv = bias[n];
#pragma unroll
            for (int rr = 0; rr < 4; ++rr) {
                int m = mbase + rr;
                float v = accH[i][j][rr] + accM[i][j][rr] * MINV + bv;
                if (LRELU) v = (v >= 0.f) ? v : NEG_SLOPE * v;
                size_t o = (size_t)m * N + n;
                if (SPLITOUT) {
                    f16 h, mm;
                    split2h(v, h, mm);
                    Cp[o] = h;
                    Cp[cPS + o] = mm;
                } else {
                    if (resid) v += resid[o];
                    C[o] = v;
                }
            }
        }
    }
}

// ---------------------------------------------------------------------------
// Single-pass plain-f16 GEMM for the vocab projection (r13-identical).
__global__ __launch_bounds__(512, 4)
void gemm_f16_1p(const f16* __restrict__ A,
                 const f16* __restrict__ Bt,
                 const float* __restrict__ bias,
                 float* __restrict__ C, int N, int K) {
    __shared__ f16 As[2][4096];
    __shared__ f16 Bs[4096];

    int chunk = gridDim.x >> 3;
    int bid = blockIdx.x;
    int sw = (bid & 7) * chunk + (bid >> 3);
    int m0 = (sw & 31) << 7;
    int n0 = (sw >> 5) << 7;

    const int tid  = threadIdx.x;
    const int lane = tid & 63;
    const int wid  = tid >> 6;

    const int ssk = (((tid & 3) ^ ((tid >> 3) & 3)) << 3);
    const size_t offA = (size_t)(m0 + (tid >> 2)) * K + ssk;
    const size_t offB = (size_t)(n0 + (tid >> 2)) * K + ssk;
    const int ldst = wid * 512;

    f32x4 acc[4][2];
#pragma unroll
    for (int i = 0; i < 4; ++i)
#pragma unroll
        for (int j = 0; j < 2; ++j) acc[i][j] = (f32x4){0.f, 0.f, 0.f, 0.f};

    const int wr = wid >> 2, wc = wid & 3;
    const int fm = lane & 15;
    const int rslot = (((lane >> 4) ^ ((lane >> 1) & 3)) & 3) << 3;
    const int foffA0 = (wr * 64 + fm) * 32 + rslot;
    const int foffB0 = (wc * 32 + fm) * 32 + rslot;

    const int nt = K >> 5;
    __builtin_amdgcn_global_load_lds((const AS1 void*)(A + offA),
                                     (AS3 void*)(&As[0][ldst]), 16, 0, 0);
    __builtin_amdgcn_global_load_lds((const AS1 void*)(Bt + offB),
                                     (AS3 void*)(&Bs[ldst]), 16, 0, 0);
    int cur = 0;
    for (int t = 0; t < nt; ++t) {
        if (t + 1 < nt) {
            __builtin_amdgcn_global_load_lds(
                (const AS1 void*)(A + offA + ((t + 1) << 5)),
                (AS3 void*)(&As[cur ^ 1][ldst]), 16, 0, 0);
            WAIT_BAR(1);
        } else {
            WAIT_BAR(0);
        }

        half8 bh[2];
#pragma unroll
        for (int j = 0; j < 2; ++j)
            bh[j] = *(const half8*)(&Bs[foffB0 + j * 512]);
        LGKM_BAR();
        if (t + 1 < nt)
            __builtin_amdgcn_global_load_lds(
                (const AS1 void*)(Bt + offB + ((t + 1) << 5)),
                (AS3 void*)(&Bs[ldst]), 16, 0, 0);

#pragma unroll
        for (int i = 0; i < 4; ++i) {
            half8 ah = *(const half8*)(&As[cur][foffA0 + i * 512]);
#pragma unroll
            for (int j = 0; j < 2; ++j)
                acc[i][j] = __builtin_amdgcn_mfma_f32_16x16x32_f16(
                    ah, bh[j], acc[i][j], 0, 0, 0);
        }
        LGKM_BAR();
        cur ^= 1;
    }

#pragma unroll
    for (int i = 0; i < 4; ++i) {
        int mbase = m0 + wr * 64 + i * 16 + ((lane >> 4) << 2);
#pragma unroll
        for (int j = 0; j < 2; ++j) {
            int n = n0 + wc * 32 + j * 16 + fm;
            float bv = bias[n];
#pragma unroll
            for (int rr = 0; rr < 4; ++rr) {
                int m = mbase + rr;
                C[(size_t)m * N + n] = acc[i][j][rr] + bv;
            }
        }
    }
}

// ---------------------------------------------------------------------------
// V transpose: qkvp V region [bt][2048+h*64+e] planes -> vT [(bh*64+e)*512+t]
// planes (s-contiguous rows for the attn A-operand staging).
__global__ __launch_bounds__(256)
void vtrans(const f16* __restrict__ qkvp, size_t QPS,
            f16* __restrict__ vT, size_t VPS) {
    int bh = blockIdx.y;
    int b = bh >> 4, h = bh & 15;
    int t0 = blockIdx.x << 6;
    __shared__ f16 tile[64][72];
    const int tid = threadIdx.x;
#pragma unroll
    for (int pl = 0; pl < 2; ++pl) {
        const f16* src = qkvp + (size_t)pl * QPS + 2048 + h * 64;
#pragma unroll
        for (int it = 0; it < 2; ++it) {
            int t = (tid >> 3) + it * 32;
            int e0 = (tid & 7) << 3;
            *(half8*)&tile[t][e0] =
                *(const half8*)(src + (size_t)(b * 512 + t0 + t) * 3072 + e0);
        }
        __syncthreads();
#pragma unroll
        for (int it = 0; it < 2; ++it) {
            int e = (tid >> 3) + it * 32;
            int tc = (tid & 7) << 3;
            half8 v;
#pragma unroll
            for (int k = 0; k < 8; ++k) v[k] = tile[tc + k][e];
            *(half8*)(vT + (size_t)pl * VPS + (((size_t)(bh * 64 + e)) << 9) + t0 + tc) = v;
        }
        __syncthreads();
    }
}

// ---------------------------------------------------------------------------
// MFMA flash attention, split-f16 3-pass (f32-grade), swapped operands.
// Block: 256 thr / 4 waves; wave w owns t-rows [t0+w*16, +16) of one (b,h).
// S^T = mfma(A=K, B=Q): C col = t = lane&15 -> softmax in-lane + shfl 16/32.
// PV:  out^T = mfma(A=V^T, B=P): P restaged to wave-local LDS via b64 packs.
// LDS element offsets: Kh 0, Km 4096, Vh 8192, Vm 12288, P 16384 + wid*2048.
// XOR-slot swizzle invariant everywhere: LDS[r][slot] = global chunk slot^(r&7).
template <int CAUSAL>
__global__ __launch_bounds__(256)
void attn_mfma(const f16* __restrict__ qkvp, size_t QPS,
               const f16* __restrict__ vT, size_t VPS,
               f16* __restrict__ outp, size_t OPS) {
    __shared__ f16 lds[24576];
    const int tid  = threadIdx.x;
    const int lane = tid & 63;
    const int wid  = tid >> 6;
    const int tl   = lane & 15;
    const int g    = lane >> 4;

    int bh = blockIdx.y;
    int b = bh >> 4, h = bh & 15;
    int t0 = blockIdx.x << 6;
    const int PB = 16384 + wid * 2048;

    // Q as B-operand fragments (col=t=lane&15, k=e), 2 kf x 2 planes
    half8 Qh[2], Qm[2];
    {
        const f16* qb = qkvp + (size_t)(b * 512 + t0 + wid * 16 + tl) * 3072
                        + h * 64 + (g << 3);
        Qh[0] = *(const half8*)(qb);
        Qh[1] = *(const half8*)(qb + 32);
        Qm[0] = *(const half8*)(qb + QPS);
        Qm[1] = *(const half8*)(qb + QPS + 32);
    }

    f32x4 oH[4], oM[4];
#pragma unroll
    for (int en = 0; en < 4; ++en) {
        oH[en] = (f32x4){0.f, 0.f, 0.f, 0.f};
        oM[en] = (f32x4){0.f, 0.f, 0.f, 0.f};
    }
    float m_run = -INFINITY, l_run = 0.f;

    auto STAGE1 = [&](int ldsOff, const f16* srcBase, int rowStride) {
#pragma unroll
        for (int it = 0; it < 2; ++it) {
            int r  = (tid >> 3) + it * 32;
            int cp = (tid & 7) ^ (r & 7);
            __builtin_amdgcn_global_load_lds(
                (const AS1 void*)(srcBase + (size_t)r * rowStride + cp * 8),
                (AS3 void*)(lds + ldsOff + (it * 32 + wid * 8) * 64), 16, 0, 0);
        }
    };

    const int NT = CAUSAL ? (blockIdx.x + 1) : (T_SEQ / 64);
    for (int st = 0; st < NT; ++st) {
        int s0 = st << 6;
        {
            const f16* kS = qkvp + (size_t)(b * 512 + s0) * 3072 + 1024 + h * 64;
            const f16* vS = vT + ((size_t)(bh * 64) << 9) + s0;
            STAGE1(0,     kS, 3072);
            STAGE1(4096,  kS + QPS, 3072);
            STAGE1(8192,  vS, 512);
            STAGE1(12288, vS + VPS, 512);
        }
        __syncthreads();

        // ---- S^T = K . Q^T (3-pass) ----
        f32x4 sH[4], sM[4];
#pragma unroll
        for (int sm = 0; sm < 4; ++sm) {
            sH[sm] = (f32x4){0.f, 0.f, 0.f, 0.f};
            sM[sm] = (f32x4){0.f, 0.f, 0.f, 0.f};
        }
#pragma unroll
        for (int sm = 0; sm < 4; ++sm) {
            int sl = sm * 16 + tl;
#pragma unroll
            for (int kf = 0; kf < 2; ++kf) {
                int sp = ((kf * 4 + g) ^ (sl & 7)) << 3;
                half8 kh = *(const half8*)(lds + sl * 64 + sp);
                half8 km = *(const half8*)(lds + 4096 + sl * 64 + sp);
                sM[sm] = __builtin_amdgcn_mfma_f32_16x16x32_f16(km, Qh[kf], sM[sm], 0, 0, 0);
                sM[sm] = __builtin_amdgcn_mfma_f32_16x16x32_f16(kh, Qm[kf], sM[sm], 0, 0, 0);
                sH[sm] = __builtin_amdgcn_mfma_f32_16x16x32_f16(kh, Qh[kf], sH[sm], 0, 0, 0);
            }
        }

        // ---- softmax (row t = lane&15; stats in-lane + shfl 16,32) ----
        float sv[4][4];
#pragma unroll
        for (int sm = 0; sm < 4; ++sm)
#pragma unroll
            for (int rr = 0; rr < 4; ++rr) {
                float v = (sH[sm][rr] + sM[sm][rr] * MINV) * 8.0f;
                if (CAUSAL && st == NT - 1) {
                    int sg = s0 + sm * 16 + (g << 2) + rr;
                    int tg = t0 + wid * 16 + tl;
                    if (sg > tg) v = -INFINITY;
                }
                sv[sm][rr] = v;
            }
        float rmax = -INFINITY;
#pragma unroll
        for (int sm = 0; sm < 4; ++sm)
#pragma unroll
            for (int rr = 0; rr < 4; ++rr) rmax = fmaxf(rmax, sv[sm][rr]);
        rmax = fmaxf(rmax, __shfl_xor(rmax, 16));
        rmax = fmaxf(rmax, __shfl_xor(rmax, 32));
        float mn = fmaxf(m_run, rmax);
        float fsc = __expf(m_run - mn);
        float rs = 0.f;
#pragma unroll
        for (int sm = 0; sm < 4; ++sm)
#pragma unroll
            for (int rr = 0; rr < 4; ++rr) {
                float p = __expf(sv[sm][rr] - mn);
                sv[sm][rr] = p;
                rs += p;
            }
        rs += __shfl_xor(rs, 16);
        rs += __shfl_xor(rs, 32);
        l_run = l_run * fsc + rs;
        m_run = mn;
#pragma unroll
        for (int en = 0; en < 4; ++en)
#pragma unroll
            for (int rr = 0; rr < 4; ++rr) {
                oH[en][rr] *= fsc;
                oM[en][rr] *= fsc;
            }

        // ---- P -> wave-local LDS (split planes), b64 packs ----
#pragma unroll
        for (int sm = 0; sm < 4; ++sm) {
            half4 ph4, pm4;
#pragma unroll
            for (int rr = 0; rr < 4; ++rr) {
                f16 hh, mm;
                split2h(sv[sm][rr], hh, mm);
                ph4[rr] = hh;
                pm4[rr] = mm;
            }
            int sbase = sm * 16 + (g << 2);
            int sp = (sbase >> 3) ^ (tl & 7);
            int eo = PB + tl * 64 + sp * 8 + (sbase & 7);
            *(half4*)(lds + eo) = ph4;
            *(half4*)(lds + eo + 1024) = pm4;
        }
        asm volatile("s_waitcnt lgkmcnt(0)" ::: "memory");
        __builtin_amdgcn_sched_barrier(0);

        // ---- PV: out^T += V^T . P (3-pass) ----
        half8 Ph[2], Pm[2];
#pragma unroll
        for (int kf = 0; kf < 2; ++kf) {
            int sp = ((kf * 4 + g) ^ (tl & 7)) << 3;
            Ph[kf] = *(const half8*)(lds + PB + tl * 64 + sp);
            Pm[kf] = *(const half8*)(lds + PB + 1024 + tl * 64 + sp);
        }
#pragma unroll
        for (int en = 0; en < 4; ++en) {
            int el = en * 16 + tl;
#pragma unroll
            for (int kf = 0; kf < 2; ++kf) {
                int sp = ((kf * 4 + g) ^ (el & 7)) << 3;
                half8 vh = *(const half8*)(lds + 8192 + el * 64 + sp);
                half8 vm = *(const half8*)(lds + 12288 + el * 64 + sp);
                oM[en] = __builtin_amdgcn_mfma_f32_16x16x32_f16(vm, Ph[kf], oM[en], 0, 0, 0);
                oM[en] = __builtin_amdgcn_mfma_f32_16x16x32_f16(vh, Pm[kf], oM[en], 0, 0, 0);
                oH[en] = __builtin_amdgcn_mfma_f32_16x16x32_f16(vh, Ph[kf], oH[en], 0, 0, 0);
            }
        }
        __syncthreads();
    }

    // ---- epilogue: out col t = lane&15, row e = en*16 + g*4 + rr ----
    float inv = 1.f / l_run;
    size_t obase = (size_t)(b * 512 + t0 + wid * 16 + tl) * 1024 + h * 64;
#pragma unroll
    for (int en = 0; en < 4; ++en) {
        half4 ph4, pm4;
#pragma unroll
        for (int rr = 0; rr < 4; ++rr) {
            float v = (oH[en][rr] + oM[en][rr] * MINV) * inv;
            f16 hh, mm;
            split2h(v, hh, mm);
            ph4[rr] = hh;
            pm4[rr] = mm;
        }
        size_t oc = obase + en * 16 + (g << 2);
        *(half4*)(outp + oc) = ph4;
        *(half4*)(outp + OPS + oc) = pm4;
    }
}

// ---------------------------------------------------------------------------
extern "C" void kernel_launch(void* const* d_in, const int* in_sizes, int n_in,
                              void* d_out, int out_size, void* d_ws, size_t ws_size,
                              hipStream_t stream) {
    const int*   idx = (const int*)  d_in[0];
    const float* tok = (const float*)d_in[1];
    const float* pos = (const float*)d_in[2];
    const float* Wq  = (const float*)d_in[3];
    const float* bq  = (const float*)d_in[4];
    const float* Wk  = (const float*)d_in[5];
    const float* bk  = (const float*)d_in[6];
    const float* Wv  = (const float*)d_in[7];
    const float* bv  = (const float*)d_in[8];
    const float* Wo  = (const float*)d_in[9];
    const float* bo  = (const float*)d_in[10];
    const float* W1  = (const float*)d_in[11];
    const float* b1  = (const float*)d_in[12];
    const float* W2  = (const float*)d_in[13];
    const float* b2  = (const float*)d_in[14];
    const float* nw  = (const float*)d_in[15];
    const float* fnw = (const float*)d_in[16];
    const float* Wf  = (const float*)d_in[17];
    const float* bf  = (const float*)d_in[18];
    float* out = (float*)d_out;

    const size_t SZ   = (size_t)BT * DMODEL;    // 4M
    const size_t HSZF = (size_t)BT * DFF;       // 16M
    const size_t QPS  = (size_t)BT * QLD;       // 12.6M
    const size_t VPS  = (size_t)BATCH * NHEAD * HSZ * T_SEQ;  // 4.19M

    char* w = (char*)d_ws;
    auto alloc = [&](size_t bytes) {
        char* p = w;
        w += (bytes + 255) & ~(size_t)255;
        return p;
    };
    float* x    = (float*)alloc(SZ * 4);
    float* xo   = (float*)alloc(SZ * 4);
    f16*   xnp  = (f16*)  alloc(SZ * 2 * 2);
    f16*   qkvp = (f16*)  alloc(QPS * 2 * 2);                 // q,k,v split planes
    f16*   vTb  = (f16*)  alloc(VPS * 2 * 2);                 // transposed V planes
    f16*   aop  = (f16*)  alloc(SZ * 2 * 2);
    f16*   hbp  = (f16*)  alloc(HSZF * 2 * 2);
    char*  wreg = alloc(132ull * 1024 * 1024);
    f16*   qkvTp = (f16*)wreg;
    f16*   woTp  = qkvTp + 2ull * QLD * DMODEL;
    f16*   w1Tp  = woTp  + 2ull * DMODEL * DMODEL;
    f16*   w2Tp  = w1Tp  + 2ull * DFF * DMODEL;
    f16*   wfp   = (f16*)wreg;
    float* catb  = (float*)alloc((size_t)NLAYER * QLD * 4);

    cat_bias<<<(NLAYER * QLD) / 256, 256, 0, stream>>>(bq, bk, bv, catb);
    embed_kernel<<<BT, 256, 0, stream>>>(idx, tok, pos, x);

    for (int l = 0; l < NLAYER; ++l) {
        const float* nwl = nw + (size_t)l * DMODEL;
        const float* catbl = catb + (size_t)l * QLD;
        const float* bol = bo + (size_t)l * DMODEL;
        const float* b1l = b1 + (size_t)l * DFF;
        const float* b2l = b2 + (size_t)l * DMODEL;

        {
            long izs = (long)DMODEL * HSZ;
            long ozi = (long)HSZ * DMODEL;
            size_t ps = (size_t)QLD * DMODEL;
            dim3 gq(HSZ / 32, DMODEL / 32, NHEAD);
            const float* Wql = Wq + (size_t)l * NHEAD * DMODEL * HSZ;
            const float* Wkl = Wk + (size_t)l * NHEAD * DMODEL * HSZ;
            const float* Wvl = Wv + (size_t)l * NHEAD * DMODEL * HSZ;
            transpose_split<<<gq, 256, 0, stream>>>(Wql, qkvTp,                 ps, DMODEL, HSZ, izs, ozi);
            transpose_split<<<gq, 256, 0, stream>>>(Wkl, qkvTp + 1024ul * 1024, ps, DMODEL, HSZ, izs, ozi);
            transpose_split<<<gq, 256, 0, stream>>>(Wvl, qkvTp + 2048ul * 1024, ps, DMODEL, HSZ, izs, ozi);
            transpose_split<<<dim3(DMODEL / 32, DMODEL / 32, 1), 256, 0, stream>>>(
                Wo + (size_t)l * DMODEL * DMODEL, woTp, (size_t)DMODEL * DMODEL, DMODEL, DMODEL, 0, 0);
            transpose_split<<<dim3(DFF / 32, DMODEL / 32, 1), 256, 0, stream>>>(
                W1 + (size_t)l * DMODEL * DFF, w1Tp, (size_t)DFF * DMODEL, DMODEL, DFF, 0, 0);
            transpose_split<<<dim3(DMODEL / 32, DFF / 32, 1), 256, 0, stream>>>(
                W2 + (size_t)l * DMODEL * DFF, w2Tp, (size_t)DMODEL * DFF, DFF, DMODEL, 0, 0);
        }

        auto attn = [&](const float* resid, float* outp, int causal) {
            gemm_f16<false, true><<<dim3((BT / 128) * (QLD / 128)), 512, 0, stream>>>(
                xnp, SZ, qkvTp, (size_t)QLD * DMODEL, catbl, nullptr,
                nullptr, qkvp, QPS, QLD, DMODEL);
            vtrans<<<dim3(T_SEQ / 64, BATCH * NHEAD), 256, 0, stream>>>(qkvp, QPS, vTb, VPS);
            if (causal)
                attn_mfma<1><<<dim3(T_SEQ / 64, BATCH * NHEAD), 256, 0, stream>>>(
                    qkvp, QPS, vTb, VPS, aop, SZ);
            else
                attn_mfma<0><<<dim3(T_SEQ / 64, BATCH * NHEAD), 256, 0, stream>>>(
                    qkvp, QPS, vTb, VPS, aop, SZ);
            gemm_f16<false, false><<<dim3((BT / 128) * (DMODEL / 128)), 512, 0, stream>>>(
                aop, SZ, woTp, (size_t)DMODEL * DMODEL, bol, resid,
                outp, nullptr, 0, DMODEL, DMODEL);
        };

        // x_out1 = x + attn(rms(x), unmasked)
        rms_split<<<BT, 256, 0, stream>>>(x, nwl, xnp, SZ);
        attn(x, xo, 0);
        // x_out2 = x + ffn(rms(x_out1))      (residual from ORIGINAL x)
        rms_split<<<BT, 256, 0, stream>>>(xo, nwl, xnp, SZ);
        gemm_f16<true, true><<<dim3((BT / 128) * (DFF / 128)), 512, 0, stream>>>(
            xnp, SZ, w1Tp, (size_t)DFF * DMODEL, b1l, nullptr,
            nullptr, hbp, HSZF, DFF, DMODEL);
        gemm_f16<false, false><<<dim3((BT / 128) * (DMODEL / 128)), 512, 0, stream>>>(
            hbp, HSZF, w2Tp, (size_t)DMODEL * DFF, b2l, x,
            xo, nullptr, 0, DMODEL, DFF);
        // x = x_out2 + attn(rms(x_out2), masked)
        rms_split<<<BT, 256, 0, stream>>>(xo, nwl, xnp, SZ);
        attn(xo, x, 1);
    }

    // final: logits = rms(x, fnw) @ Wf + bf   (single-pass f16)
    rms_split<<<BT, 256, 0, stream>>>(x, fnw, xnp, SZ);
    transpose_split<<<dim3(VOCAB / 32, DMODEL / 32, 1), 256, 0, stream>>>(
        Wf, wfp, (size_t)VOCAB * DMODEL, DMODEL, VOCAB, 0, 0);
    gemm_f16_1p<<<dim3((BT / 128) * (VOCAB / 128)), 512, 0, stream>>>(
        xnp, wfp, bf, out, VOCAB, DMODEL);
}

// Round 15
// 6125.344 us; speedup vs baseline: 2.3129x; 1.0047x over previous
//
#include <hip/hip_runtime.h>
#include <hip/hip_bf16.h>
#include <cstdint>
#include <cstddef>

#define T_SEQ   512
#define BATCH   8
#define BT      4096
#define DMODEL  1024
#define NHEAD   16
#define HSZ     64
#define NLAYER  8
#define DFF     4096
#define VOCAB   32000
#define EPS     1e-6f
#define NEG_SLOPE 0.1f
#define QLD     3072
#define MSCALE  2048.0f
#define MINV    (1.0f / 2048.0f)

typedef _Float16 f16;
typedef __attribute__((ext_vector_type(8))) _Float16 half8;
typedef __attribute__((ext_vector_type(4))) _Float16 half4;
typedef __attribute__((ext_vector_type(4))) float f32x4;

#define AS1 __attribute__((address_space(1)))
#define AS3 __attribute__((address_space(3)))

#define WAIT_BAR(N) asm volatile("s_waitcnt vmcnt(" #N ")\ns_barrier" ::: "memory")
#define LGKM_BAR()  asm volatile("s_waitcnt lgkmcnt(0)\ns_barrier" ::: "memory")

// ---------------------------------------------------------------------------
__global__ void embed_kernel(const int* __restrict__ idx,
                             const float* __restrict__ tok,
                             const float* __restrict__ pos,
                             float* __restrict__ x) {
    int bt  = blockIdx.x;
    int tid = threadIdx.x;
    int token = idx[bt];
    int t = bt & (T_SEQ - 1);
    float4 a = reinterpret_cast<const float4*>(tok + (size_t)token * DMODEL)[tid];
    float4 p = reinterpret_cast<const float4*>(pos + (size_t)t * DMODEL)[tid];
    reinterpret_cast<float4*>(x + (size_t)bt * DMODEL)[tid] =
        make_float4(a.x + p.x, a.y + p.y, a.z + p.z, a.w + p.w);
}

// ---------------------------------------------------------------------------
__device__ __forceinline__ void split2h(float v, f16& h, f16& m) {
    f16 hh = (f16)v;
    float hf = (float)hh;
    if (fabsf(hf) < 6.103515625e-05f) { hh = (f16)0.0f; hf = 0.0f; }
    h = hh;
    m = (f16)((v - hf) * MSCALE);
}

// ---------------------------------------------------------------------------
__global__ void rms_split(const float* __restrict__ x,
                          const float* __restrict__ w,
                          f16* __restrict__ out, size_t planeStride) {
    int row = blockIdx.x;
    int tid = threadIdx.x;
    float4 v = reinterpret_cast<const float4*>(x + (size_t)row * DMODEL)[tid];
    float ss = v.x * v.x + v.y * v.y + v.z * v.z + v.w * v.w;
#pragma unroll
    for (int off = 32; off > 0; off >>= 1) ss += __shfl_xor(ss, off);
    __shared__ float wsum[4];
    if ((tid & 63) == 0) wsum[tid >> 6] = ss;
    __syncthreads();
    float tot = wsum[0] + wsum[1] + wsum[2] + wsum[3];
    float scale = rsqrtf(tot * (1.0f / DMODEL) + EPS);
    float4 wv = reinterpret_cast<const float4*>(w)[tid];
    float o[4] = {v.x * scale * wv.x, v.y * scale * wv.y,
                  v.z * scale * wv.z, v.w * scale * wv.w};
    size_t base = (size_t)row * DMODEL + tid * 4;
#pragma unroll
    for (int j = 0; j < 4; ++j) {
        f16 h, m;
        split2h(o[j], h, m);
        out[base + j] = h;
        out[planeStride + base + j] = m;
    }
}

// ---------------------------------------------------------------------------
__global__ __launch_bounds__(256)
void transpose_split(const float* __restrict__ in, f16* __restrict__ out,
                     size_t planeStride, int R, int C,
                     long izs, long ozi) {
    int z = blockIdx.z;
    in  += (size_t)z * izs;
    out += (size_t)z * ozi;
    __shared__ float tile[32][33];
    int r0 = blockIdx.y << 5, c0 = blockIdx.x << 5;
    int tx = threadIdx.x & 31, ty = threadIdx.x >> 5;
#pragma unroll
    for (int i = 0; i < 4; ++i) {
        int r = ty + (i << 3);
        tile[r][tx] = in[(size_t)(r0 + r) * C + c0 + tx];
    }
    __syncthreads();
#pragma unroll
    for (int i = 0; i < 4; ++i) {
        int c = ty + (i << 3);
        float v = tile[tx][c];
        size_t o = (size_t)(c0 + c) * R + r0 + tx;
        f16 h, m;
        split2h(v, h, m);
        out[o] = h;
        out[planeStride + o] = m;
    }
}

// concat per-layer qkv bias into (L, 3072) f32
__global__ void cat_bias(const float* __restrict__ bq, const float* __restrict__ bk,
                         const float* __restrict__ bv, float* __restrict__ cb) {
    int i = blockIdx.x * 256 + threadIdx.x;
    int l = i / QLD, r = i - l * QLD;
    const float* src = (r < 1024) ? bq : ((r < 2048) ? bk : bv);
    cb[i] = src[l * 1024 + (r & 1023)];
}

// ---------------------------------------------------------------------------
// f16 split-GEMM: 3 passes, 2 accumulators, B-single-buffer, end-of-body
// LGKM_BAR (r13 sync protocol, canary-validated).
// VOUT: for the QKV GEMM, blocks with n0 >= 2048 (the V projection) write the
// TRANSPOSED V planes (vT[(bh*64+e)*512 + t]) instead of qkvp -- bitwise the
// same values the old vtrans kernel produced, minus a kernel + dead stores.
template <bool LRELU, bool SPLITOUT, bool VOUT>
__global__ __launch_bounds__(512, 4)
void gemm_f16(const f16* __restrict__ A, size_t aPS,
              const f16* __restrict__ Bt, size_t bPS,
              const float* __restrict__ bias,
              const float* __restrict__ resid,
              float* __restrict__ C, f16* __restrict__ Cp, size_t cPS,
              f16* __restrict__ vTp, size_t vPS,
              int N, int K) {
    __shared__ f16 As[2][2 * 4096];
    __shared__ f16 Bs[2 * 4096];

    int chunk = gridDim.x >> 3;
    int bid = blockIdx.x;
    int sw = (bid & 7) * chunk + (bid >> 3);
    int m0 = (sw & 31) << 7;
    int n0 = (sw >> 5) << 7;

    const int tid  = threadIdx.x;
    const int lane = tid & 63;
    const int wid  = tid >> 6;

    const int ssk = (((tid & 3) ^ ((tid >> 3) & 3)) << 3);
    const size_t offA = (size_t)(m0 + (tid >> 2)) * K + ssk;
    const size_t offB = (size_t)(n0 + (tid >> 2)) * K + ssk;
    const int ldst = wid * 512;

    f32x4 accH[4][2], accM[4][2];
#pragma unroll
    for (int i = 0; i < 4; ++i)
#pragma unroll
        for (int j = 0; j < 2; ++j) {
            accH[i][j] = (f32x4){0.f, 0.f, 0.f, 0.f};
            accM[i][j] = (f32x4){0.f, 0.f, 0.f, 0.f};
        }

    const int wr = wid >> 2, wc = wid & 3;
    const int fm = lane & 15;
    const int rslot = (((lane >> 4) ^ ((lane >> 1) & 3)) & 3) << 3;
    const int foffA0 = (wr * 64 + fm) * 32 + rslot;
    const int foffB0 = (wc * 32 + fm) * 32 + rslot;

    auto STAGE_A = [&](int buf, int k0) {
#pragma unroll
        for (int pp = 0; pp < 2; ++pp)
            __builtin_amdgcn_global_load_lds(
                (const AS1 void*)(A + pp * aPS + offA + k0),
                (AS3 void*)(&As[buf][pp * 4096 + ldst]), 16, 0, 0);
    };
    auto STAGE_B = [&](int k0) {
#pragma unroll
        for (int pp = 0; pp < 2; ++pp)
            __builtin_amdgcn_global_load_lds(
                (const AS1 void*)(Bt + pp * bPS + offB + k0),
                (AS3 void*)(&Bs[pp * 4096 + ldst]), 16, 0, 0);
    };

    const int nt = K >> 5;
    STAGE_A(0, 0);
    STAGE_B(0);
    int cur = 0;
    for (int t = 0; t < nt; ++t) {
        if (t + 1 < nt) {
            STAGE_A(cur ^ 1, (t + 1) << 5);
            WAIT_BAR(2);
        } else {
            WAIT_BAR(0);
        }

        half8 bh[2], bm[2];
#pragma unroll
        for (int j = 0; j < 2; ++j) {
            bh[j] = *(const half8*)(&Bs[foffB0 + j * 512]);
            bm[j] = *(const half8*)(&Bs[4096 + foffB0 + j * 512]);
        }
        LGKM_BAR();
        if (t + 1 < nt) STAGE_B((t + 1) << 5);

#pragma unroll
        for (int i = 0; i < 4; ++i) {
            half8 ah = *(const half8*)(&As[cur][foffA0 + i * 512]);
            half8 am = *(const half8*)(&As[cur][4096 + foffA0 + i * 512]);
#pragma unroll
            for (int j = 0; j < 2; ++j) {
                accM[i][j] = __builtin_amdgcn_mfma_f32_16x16x32_f16(
                    am, bh[j], accM[i][j], 0, 0, 0);
                accM[i][j] = __builtin_amdgcn_mfma_f32_16x16x32_f16(
                    ah, bm[j], accM[i][j], 0, 0, 0);
                accH[i][j] = __builtin_amdgcn_mfma_f32_16x16x32_f16(
                    ah, bh[j], accH[i][j], 0, 0, 0);
            }
        }
        LGKM_BAR();
        cur ^= 1;
    }

    const bool vblock = VOUT && (n0 >= 2048);
#pragma unroll
    for (int i = 0; i < 4; ++i) {
        int mbase = m0 + wr * 64 + i * 16 + ((lane >> 4) << 2);
#pragma unroll
        for (int j = 0; j < 2; ++j) {
            int n = n0 + wc * 32 + j * 16 + fm;
            float bv = bias[n];
            if (vblock) {
                // transposed V write: 4 consecutive t per half4
                half4 ph4, pm4;
#pragma unroll
                for (int rr = 0; rr < 4; ++rr) {
                    float v = accH[i][j][rr] + accM[i][j][rr] * MINV + bv;
                    f16 hh, mm;
                    split2h(v, hh, mm);
                    ph4[rr] = hh;
                    pm4[rr] = mm;
                }
                int nn = n - 2048;
                int bb = mbase >> 9, tt = mbase & 511;
                size_t vo = (((size_t)(bb * 16 + (nn >> 6)) * 64 + (nn & 63)) << 9) + tt;
                *(half4*)(vTp + vo) = ph4;
                *(half4*)(vTp + vPS + vo) = pm4;
            } else {
#pragma unroll
                for (int rr = 0; rr < 4; ++rr) {
                    int m = mbase + rr;
                    float v = accH[i][j][rr] + accM[i][j][rr] * MINV + bv;
                    if (LRELU) v = (v >= 0.f) ? v : NEG_SLOPE * v;
                    size_t o = (size_t)m * N + n;
                    if (SPLITOUT) {
                        f16 h, mm;
                        split2h(v, h, mm);
                        Cp[o] = h;
                        Cp[cPS + o] = mm;
                    } else {
                        if (resid) v += resid[o];
                        C[o] = v;
                    }
                }
            }
        }
    }
}

// ---------------------------------------------------------------------------
// Single-pass plain-f16 GEMM for the vocab projection; C stream written
// nontemporal (write-once, never re-read) to keep A/B L2/L3-resident.
__global__ __launch_bounds__(512, 4)
void gemm_f16_1p(const f16* __restrict__ A,
                 const f16* __restrict__ Bt,
                 const float* __restrict__ bias,
                 float* __restrict__ C, int N, int K) {
    __shared__ f16 As[2][4096];
    __shared__ f16 Bs[4096];

    int chunk = gridDim.x >> 3;
    int bid = blockIdx.x;
    int sw = (bid & 7) * chunk + (bid >> 3);
    int m0 = (sw & 31) << 7;
    int n0 = (sw >> 5) << 7;

    const int tid  = threadIdx.x;
    const int lane = tid & 63;
    const int wid  = tid >> 6;

    const int ssk = (((tid & 3) ^ ((tid >> 3) & 3)) << 3);
    const size_t offA = (size_t)(m0 + (tid >> 2)) * K + ssk;
    const size_t offB = (size_t)(n0 + (tid >> 2)) * K + ssk;
    const int ldst = wid * 512;

    f32x4 acc[4][2];
#pragma unroll
    for (int i = 0; i < 4; ++i)
#pragma unroll
        for (int j = 0; j < 2; ++j) acc[i][j] = (f32x4){0.f, 0.f, 0.f, 0.f};

    const int wr = wid >> 2, wc = wid & 3;
    const int fm = lane & 15;
    const int rslot = (((lane >> 4) ^ ((lane >> 1) & 3)) & 3) << 3;
    const int foffA0 = (wr * 64 + fm) * 32 + rslot;
    const int foffB0 = (wc * 32 + fm) * 32 + rslot;

    const int nt = K >> 5;
    __builtin_amdgcn_global_load_lds((const AS1 void*)(A + offA),
                                     (AS3 void*)(&As[0][ldst]), 16, 0, 0);
    __builtin_amdgcn_global_load_lds((const AS1 void*)(Bt + offB),
                                     (AS3 void*)(&Bs[ldst]), 16, 0, 0);
    int cur = 0;
    for (int t = 0; t < nt; ++t) {
        if (t + 1 < nt) {
            __builtin_amdgcn_global_load_lds(
                (const AS1 void*)(A + offA + ((t + 1) << 5)),
                (AS3 void*)(&As[cur ^ 1][ldst]), 16, 0, 0);
            WAIT_BAR(1);
        } else {
            WAIT_BAR(0);
        }

        half8 bh[2];
#pragma unroll
        for (int j = 0; j < 2; ++j)
            bh[j] = *(const half8*)(&Bs[foffB0 + j * 512]);
        LGKM_BAR();
        if (t + 1 < nt)
            __builtin_amdgcn_global_load_lds(
                (const AS1 void*)(Bt + offB + ((t + 1) << 5)),
                (AS3 void*)(&Bs[ldst]), 16, 0, 0);

#pragma unroll
        for (int i = 0; i < 4; ++i) {
            half8 ah = *(const half8*)(&As[cur][foffA0 + i * 512]);
#pragma unroll
            for (int j = 0; j < 2; ++j)
                acc[i][j] = __builtin_amdgcn_mfma_f32_16x16x32_f16(
                    ah, bh[j], acc[i][j], 0, 0, 0);
        }
        LGKM_BAR();
        cur ^= 1;
    }

#pragma unroll
    for (int i = 0; i < 4; ++i) {
        int mbase = m0 + wr * 64 + i * 16 + ((lane >> 4) << 2);
#pragma unroll
        for (int j = 0; j < 2; ++j) {
            int n = n0 + wc * 32 + j * 16 + fm;
            float bv = bias[n];
#pragma unroll
            for (int rr = 0; rr < 4; ++rr) {
                int m = mbase + rr;
                __builtin_nontemporal_store(acc[i][j][rr] + bv,
                                            C + (size_t)m * N + n);
            }
        }
    }
}

// ---------------------------------------------------------------------------
// MFMA flash attention, split-f16 3-pass (f32-grade), swapped operands
// (r14-identical, canary-validated).
template <int CAUSAL>
__global__ __launch_bounds__(256)
void attn_mfma(const f16* __restrict__ qkvp, size_t QPS,
               const f16* __restrict__ vT, size_t VPS,
               f16* __restrict__ outp, size_t OPS) {
    __shared__ f16 lds[24576];
    const int tid  = threadIdx.x;
    const int lane = tid & 63;
    const int wid  = tid >> 6;
    const int tl   = lane & 15;
    const int g    = lane >> 4;

    int bh = blockIdx.y;
    int b = bh >> 4, h = bh & 15;
    int t0 = blockIdx.x << 6;
    const int PB = 16384 + wid * 2048;

    half8 Qh[2], Qm[2];
    {
        const f16* qb = qkvp + (size_t)(b * 512 + t0 + wid * 16 + tl) * 3072
                        + h * 64 + (g << 3);
        Qh[0] = *(const half8*)(qb);
        Qh[1] = *(const half8*)(qb + 32);
        Qm[0] = *(const half8*)(qb + QPS);
        Qm[1] = *(const half8*)(qb + QPS + 32);
    }

    f32x4 oH[4], oM[4];
#pragma unroll
    for (int en = 0; en < 4; ++en) {
        oH[en] = (f32x4){0.f, 0.f, 0.f, 0.f};
        oM[en] = (f32x4){0.f, 0.f, 0.f, 0.f};
    }
    float m_run = -INFINITY, l_run = 0.f;

    auto STAGE1 = [&](int ldsOff, const f16* srcBase, int rowStride) {
#pragma unroll
        for (int it = 0; it < 2; ++it) {
            int r  = (tid >> 3) + it * 32;
            int cp = (tid & 7) ^ (r & 7);
            __builtin_amdgcn_global_load_lds(
                (const AS1 void*)(srcBase + (size_t)r * rowStride + cp * 8),
                (AS3 void*)(lds + ldsOff + (it * 32 + wid * 8) * 64), 16, 0, 0);
        }
    };

    const int NT = CAUSAL ? (blockIdx.x + 1) : (T_SEQ / 64);
    for (int st = 0; st < NT; ++st) {
        int s0 = st << 6;
        {
            const f16* kS = qkvp + (size_t)(b * 512 + s0) * 3072 + 1024 + h * 64;
            const f16* vS = vT + ((size_t)(bh * 64) << 9) + s0;
            STAGE1(0,     kS, 3072);
            STAGE1(4096,  kS + QPS, 3072);
            STAGE1(8192,  vS, 512);
            STAGE1(12288, vS + VPS, 512);
        }
        __syncthreads();

        f32x4 sH[4], sM[4];
#pragma unroll
        for (int sm = 0; sm < 4; ++sm) {
            sH[sm] = (f32x4){0.f, 0.f, 0.f, 0.f};
            sM[sm] = (f32x4){0.f, 0.f, 0.f, 0.f};
        }
#pragma unroll
        for (int sm = 0; sm < 4; ++sm) {
            int sl = sm * 16 + tl;
#pragma unroll
            for (int kf = 0; kf < 2; ++kf) {
                int sp = ((kf * 4 + g) ^ (sl & 7)) << 3;
                half8 kh = *(const half8*)(lds + sl * 64 + sp);
                half8 km = *(const half8*)(lds + 4096 + sl * 64 + sp);
                sM[sm] = __builtin_amdgcn_mfma_f32_16x16x32_f16(km, Qh[kf], sM[sm], 0, 0, 0);
                sM[sm] = __builtin_amdgcn_mfma_f32_16x16x32_f16(kh, Qm[kf], sM[sm], 0, 0, 0);
                sH[sm] = __builtin_amdgcn_mfma_f32_16x16x32_f16(kh, Qh[kf], sH[sm], 0, 0, 0);
            }
        }

        float sv[4][4];
#pragma unroll
        for (int sm = 0; sm < 4; ++sm)
#pragma unroll
            for (int rr = 0; rr < 4; ++rr) {
                float v = (sH[sm][rr] + sM[sm][rr] * MINV) * 8.0f;
                if (CAUSAL && st == NT - 1) {
                    int sg = s0 + sm * 16 + (g << 2) + rr;
                    int tg = t0 + wid * 16 + tl;
                    if (sg > tg) v = -INFINITY;
                }
                sv[sm][rr] = v;
            }
        float rmax = -INFINITY;
#pragma unroll
        for (int sm = 0; sm < 4; ++sm)
#pragma unroll
            for (int rr = 0; rr < 4; ++rr) rmax = fmaxf(rmax, sv[sm][rr]);
        rmax = fmaxf(rmax, __shfl_xor(rmax, 16));
        rmax = fmaxf(rmax, __shfl_xor(rmax, 32));
        float mn = fmaxf(m_run, rmax);
        float fsc = __expf(m_run - mn);
        float rs = 0.f;
#pragma unroll
        for (int sm = 0; sm < 4; ++sm)
#pragma unroll
            for (int rr = 0; rr < 4; ++rr) {
                float p = __expf(sv[sm][rr] - mn);
                sv[sm][rr] = p;
                rs += p;
            }
        rs += __shfl_xor(rs, 16);
        rs += __shfl_xor(rs, 32);
        l_run = l_run * fsc + rs;
        m_run = mn;
#pragma unroll
        for (int en = 0; en < 4; ++en)
#pragma unroll
            for (int rr = 0; rr < 4; ++rr) {
                oH[en][rr] *= fsc;
                oM[en][rr] *= fsc;
            }

#pragma unroll
        for (int sm = 0; sm < 4; ++sm) {
            half4 ph4, pm4;
#pragma unroll
            for (int rr = 0; rr < 4; ++rr) {
                f16 hh, mm;
                split2h(sv[sm][rr], hh, mm);
                ph4[rr] = hh;
                pm4[rr] = mm;
            }
            int sbase = sm * 16 + (g << 2);
            int sp = (sbase >> 3) ^ (tl & 7);
            int eo = PB + tl * 64 + sp * 8 + (sbase & 7);
            *(half4*)(lds + eo) = ph4;
            *(half4*)(lds + eo + 1024) = pm4;
        }
        asm volatile("s_waitcnt lgkmcnt(0)" ::: "memory");
        __builtin_amdgcn_sched_barrier(0);

        half8 Ph[2], Pm[2];
#pragma unroll
        for (int kf = 0; kf < 2; ++kf) {
            int sp = ((kf * 4 + g) ^ (tl & 7)) << 3;
            Ph[kf] = *(const half8*)(lds + PB + tl * 64 + sp);
            Pm[kf] = *(const half8*)(lds + PB + 1024 + tl * 64 + sp);
        }
#pragma unroll
        for (int en = 0; en < 4; ++en) {
            int el = en * 16 + tl;
#pragma unroll
            for (int kf = 0; kf < 2; ++kf) {
                int sp = ((kf * 4 + g) ^ (el & 7)) << 3;
                half8 vh = *(const half8*)(lds + 8192 + el * 64 + sp);
                half8 vm = *(const half8*)(lds + 12288 + el * 64 + sp);
                oM[en] = __builtin_amdgcn_mfma_f32_16x16x32_f16(vm, Ph[kf], oM[en], 0, 0, 0);
                oM[en] = __builtin_amdgcn_mfma_f32_16x16x32_f16(vh, Pm[kf], oM[en], 0, 0, 0);
                oH[en] = __builtin_amdgcn_mfma_f32_16x16x32_f16(vh, Ph[kf], oH[en], 0, 0, 0);
            }
        }
        __syncthreads();
    }

    float inv = 1.f / l_run;
    size_t obase = (size_t)(b * 512 + t0 + wid * 16 + tl) * 1024 + h * 64;
#pragma unroll
    for (int en = 0; en < 4; ++en) {
        half4 ph4, pm4;
#pragma unroll
        for (int rr = 0; rr < 4; ++rr) {
            float v = (oH[en][rr] + oM[en][rr] * MINV) * inv;
            f16 hh, mm;
            split2h(v, hh, mm);
            ph4[rr] = hh;
            pm4[rr] = mm;
        }
        size_t oc = obase + en * 16 + (g << 2);
        *(half4*)(outp + oc) = ph4;
        *(half4*)(outp + OPS + oc) = pm4;
    }
}

// ---------------------------------------------------------------------------
extern "C" void kernel_launch(void* const* d_in, const int* in_sizes, int n_in,
                              void* d_out, int out_size, void* d_ws, size_t ws_size,
                              hipStream_t stream) {
    const int*   idx = (const int*)  d_in[0];
    const float* tok = (const float*)d_in[1];
    const float* pos = (const float*)d_in[2];
    const float* Wq  = (const float*)d_in[3];
    const float* bq  = (const float*)d_in[4];
    const float* Wk  = (const float*)d_in[5];
    const float* bk  = (const float*)d_in[6];
    const float* Wv  = (const float*)d_in[7];
    const float* bv  = (const float*)d_in[8];
    const float* Wo  = (const float*)d_in[9];
    const float* bo  = (const float*)d_in[10];
    const float* W1  = (const float*)d_in[11];
    const float* b1  = (const float*)d_in[12];
    const float* W2  = (const float*)d_in[13];
    const float* b2  = (const float*)d_in[14];
    const float* nw  = (const float*)d_in[15];
    const float* fnw = (const float*)d_in[16];
    const float* Wf  = (const float*)d_in[17];
    const float* bf  = (const float*)d_in[18];
    float* out = (float*)d_out;

    const size_t SZ   = (size_t)BT * DMODEL;
    const size_t HSZF = (size_t)BT * DFF;
    const size_t QPS  = (size_t)BT * QLD;
    const size_t VPS  = (size_t)BATCH * NHEAD * HSZ * T_SEQ;

    char* w = (char*)d_ws;
    auto alloc = [&](size_t bytes) {
        char* p = w;
        w += (bytes + 255) & ~(size_t)255;
        return p;
    };
    float* x    = (float*)alloc(SZ * 4);
    float* xo   = (float*)alloc(SZ * 4);
    f16*   xnp  = (f16*)  alloc(SZ * 2 * 2);
    f16*   qkvp = (f16*)  alloc(QPS * 2 * 2);
    f16*   vTb  = (f16*)  alloc(VPS * 2 * 2);
    f16*   aop  = (f16*)  alloc(SZ * 2 * 2);
    f16*   hbp  = (f16*)  alloc(HSZF * 2 * 2);
    char*  wreg = alloc(132ull * 1024 * 1024);
    f16*   qkvTp = (f16*)wreg;
    f16*   woTp  = qkvTp + 2ull * QLD * DMODEL;
    f16*   w1Tp  = woTp  + 2ull * DMODEL * DMODEL;
    f16*   w2Tp  = w1Tp  + 2ull * DFF * DMODEL;
    f16*   wfp   = (f16*)wreg;
    float* catb  = (float*)alloc((size_t)NLAYER * QLD * 4);

    cat_bias<<<(NLAYER * QLD) / 256, 256, 0, stream>>>(bq, bk, bv, catb);
    embed_kernel<<<BT, 256, 0, stream>>>(idx, tok, pos, x);

    for (int l = 0; l < NLAYER; ++l) {
        const float* nwl = nw + (size_t)l * DMODEL;
        const float* catbl = catb + (size_t)l * QLD;
        const float* bol = bo + (size_t)l * DMODEL;
        const float* b1l = b1 + (size_t)l * DFF;
        const float* b2l = b2 + (size_t)l * DMODEL;

        {
            long izs = (long)DMODEL * HSZ;
            long ozi = (long)HSZ * DMODEL;
            size_t ps = (size_t)QLD * DMODEL;
            dim3 gq(HSZ / 32, DMODEL / 32, NHEAD);
            const float* Wql = Wq + (size_t)l * NHEAD * DMODEL * HSZ;
            const float* Wkl = Wk + (size_t)l * NHEAD * DMODEL * HSZ;
            const float* Wvl = Wv + (size_t)l * NHEAD * DMODEL * HSZ;
            transpose_split<<<gq, 256, 0, stream>>>(Wql, qkvTp,                 ps, DMODEL, HSZ, izs, ozi);
            transpose_split<<<gq, 256, 0, stream>>>(Wkl, qkvTp + 1024ul * 1024, ps, DMODEL, HSZ, izs, ozi);
            transpose_split<<<gq, 256, 0, stream>>>(Wvl, qkvTp + 2048ul * 1024, ps, DMODEL, HSZ, izs, ozi);
            transpose_split<<<dim3(DMODEL / 32, DMODEL / 32, 1), 256, 0, stream>>>(
                Wo + (size_t)l * DMODEL * DMODEL, woTp, (size_t)DMODEL * DMODEL, DMODEL, DMODEL, 0, 0);
            transpose_split<<<dim3(DFF / 32, DMODEL / 32, 1), 256, 0, stream>>>(
                W1 + (size_t)l * DMODEL * DFF, w1Tp, (size_t)DFF * DMODEL, DMODEL, DFF, 0, 0);
            transpose_split<<<dim3(DMODEL / 32, DFF / 32, 1), 256, 0, stream>>>(
                W2 + (size_t)l * DMODEL * DFF, w2Tp, (size_t)DMODEL * DFF, DFF, DMODEL, 0, 0);
        }

        auto attn = [&](const float* resid, float* outp, int causal) {
            gemm_f16<false, true, true><<<dim3((BT / 128) * (QLD / 128)), 512, 0, stream>>>(
                xnp, SZ, qkvTp, (size_t)QLD * DMODEL, catbl, nullptr,
                nullptr, qkvp, QPS, vTb, VPS, QLD, DMODEL);
            if (causal)
                attn_mfma<1><<<dim3(T_SEQ / 64, BATCH * NHEAD), 256, 0, stream>>>(
                    qkvp, QPS, vTb, VPS, aop, SZ);
            else
                attn_mfma<0><<<dim3(T_SEQ / 64, BATCH * NHEAD), 256, 0, stream>>>(
                    qkvp, QPS, vTb, VPS, aop, SZ);
            gemm_f16<false, false, false><<<dim3((BT / 128) * (DMODEL / 128)), 512, 0, stream>>>(
                aop, SZ, woTp, (size_t)DMODEL * DMODEL, bol, resid,
                outp, nullptr, 0, nullptr, 0, DMODEL, DMODEL);
        };

        // x_out1 = x + attn(rms(x), unmasked)
        rms_split<<<BT, 256, 0, stream>>>(x, nwl, xnp, SZ);
        attn(x, xo, 0);
        // x_out2 = x + ffn(rms(x_out1))      (residual from ORIGINAL x)
        rms_split<<<BT, 256, 0, stream>>>(xo, nwl, xnp, SZ);
        gemm_f16<true, true, false><<<dim3((BT / 128) * (DFF / 128)), 512, 0, stream>>>(
            xnp, SZ, w1Tp, (size_t)DFF * DMODEL, b1l, nullptr,
            nullptr, hbp, HSZF, nullptr, 0, DFF, DMODEL);
        gemm_f16<false, false, false><<<dim3((BT / 128) * (DMODEL / 128)), 512, 0, stream>>>(
            hbp, HSZF, w2Tp, (size_t)DMODEL * DFF, b2l, x,
            xo, nullptr, 0, nullptr, 0, DMODEL, DFF);
        // x = x_out2 + attn(rms(x_out2), masked)
        rms_split<<<BT, 256, 0, stream>>>(xo, nwl, xnp, SZ);
        attn(xo, x, 1);
    }

    // final: logits = rms(x, fnw) @ Wf + bf   (single-pass f16, NT stores)
    rms_split<<<BT, 256, 0, stream>>>(x, fnw, xnp, SZ);
    transpose_split<<<dim3(VOCAB / 32, DMODEL / 32, 1), 256, 0, stream>>>(
        Wf, wfp, (size_t)VOCAB * DMODEL, DMODEL, VOCAB, 0, 0);
    gemm_f16_1p<<<dim3((BT / 128) * (VOCAB / 128)), 512, 0, stream>>>(
        xnp, wfp, bf, out, VOCAB, DMODEL);
}